// Round 7
// baseline (763.013 us; speedup 1.0000x reference)
//
#include <hip/hip_runtime.h>
#include <math.h>

#define Bn 256
#define Tn 256

__constant__ int EB[32] = {0,3,5,8,10,13,15,18,22,25,29,33,38,42,48,53,59,66,73,80,89,97,107,117,128,140,153,167,183,199,216,256};

__device__ __forceinline__ float fsig(float x){ return __builtin_amdgcn_rcpf(1.f + __expf(-x)); }
__device__ __forceinline__ float ftanh(float x){ return 1.f - 2.f*__builtin_amdgcn_rcpf(1.f + __expf(2.f*x)); }

__device__ __forceinline__ void gload16(const float* g, float* l){
  __builtin_amdgcn_global_load_lds((const __attribute__((address_space(1))) void*)g,
                                   (__attribute__((address_space(3))) void*)l, 16, 0, 0);
}

#define KEEP(x) asm volatile("" : "+v"(x))

#define DOT16(res, X, W) do{ float _s0=0.f,_s1=0.f,_s2=0.f,_s3=0.f; \
  _Pragma("unroll") for (int _e=0;_e<4;++_e){ \
    _s0=fmaf((X)[_e],(W)[_e],_s0); _s1=fmaf((X)[4+_e],(W)[4+_e],_s1); \
    _s2=fmaf((X)[8+_e],(W)[8+_e],_s2); _s3=fmaf((X)[12+_e],(W)[12+_e],_s3);} \
  (res)=(_s0+_s1)+(_s2+_s3); }while(0)

#define DOT8(res, X, W) do{ float _s0=0.f,_s1=0.f; \
  _Pragma("unroll") for (int _e=0;_e<4;++_e){ \
    _s0=fmaf((X)[_e],(W)[_e],_s0); _s1=fmaf((X)[4+_e],(W)[4+_e],_s1);} \
  (res)=_s0+_s1; }while(0)

#define FMA44(A, X, W) do{ \
  (A)[0]=fmaf((X).x,(W)[0].x,(A)[0]); (A)[1]=fmaf((X).x,(W)[0].y,(A)[1]); (A)[2]=fmaf((X).x,(W)[0].z,(A)[2]); (A)[3]=fmaf((X).x,(W)[0].w,(A)[3]); \
  (A)[0]=fmaf((X).y,(W)[1].x,(A)[0]); (A)[1]=fmaf((X).y,(W)[1].y,(A)[1]); (A)[2]=fmaf((X).y,(W)[1].z,(A)[2]); (A)[3]=fmaf((X).y,(W)[1].w,(A)[3]); \
  (A)[0]=fmaf((X).z,(W)[2].x,(A)[0]); (A)[1]=fmaf((X).z,(W)[2].y,(A)[1]); (A)[2]=fmaf((X).z,(W)[2].z,(A)[2]); (A)[3]=fmaf((X).z,(W)[2].w,(A)[3]); \
  (A)[0]=fmaf((X).w,(W)[3].x,(A)[0]); (A)[1]=fmaf((X).w,(W)[3].y,(A)[1]); (A)[2]=fmaf((X).w,(W)[3].z,(A)[2]); (A)[3]=fmaf((X).w,(W)[3].w,(A)[3]); \
}while(0)

// ---------- k0: weight prep (extended: + wih1T, wB2T, bB2)
__global__ __launch_bounds__(256) void k0(const float* __restrict__ wfc, const float* __restrict__ bfc,
    const float* __restrict__ wih0, const float* __restrict__ bih0,
    const float* __restrict__ wih1,
    const float* __restrict__ glw_ih, const float* __restrict__ glb_ih,
    const float* __restrict__ ghw_ih, const float* __restrict__ ghb_ih,
    float* __restrict__ wcT, float* __restrict__ bc,
    float* __restrict__ wBT, float* __restrict__ bB,
    float* __restrict__ wih1T, float* __restrict__ wB2T, float* __restrict__ bB2){
  int i = blockIdx.x*256 + threadIdx.x;
  if (i < 6144){
    int k = i/96, o = i - (i/96)*96;
    float s = 0.f;
    #pragma unroll
    for (int kk = 0; kk < 32; ++kk) s = fmaf(wih0[o*32+kk], wfc[kk*64+k], s);
    wcT[i] = s;
  } else if (i < 6240){
    int o = i - 6144;
    float s = bih0[o];
    #pragma unroll
    for (int kk = 0; kk < 32; ++kk) s = fmaf(wih0[o*32+kk], bfc[kk], s);
    bc[o] = s;
  } else if (i < 13920){
    int j = i - 6240;
    if (j < 6144){
      int og = j >> 7, rem = j & 127, k = rem >> 2, jj = rem & 3;
      int o = og*4 + jj; int g = o/96, r = o - g*96;
      wBT[j] = glw_ih[(g*96 + r)*32 + k];          // low layer0
    } else {
      int j2 = j - 6144;
      int oh = j2 >> 6, rem = j2 & 63, k = rem >> 2, jj = rem & 3;
      int o = oh*4 + jj; int g = o/48, r = o - g*48;
      wBT[j] = ghw_ih[(g*48 + r)*16 + k];          // high
    }
  } else if (i < 14208){
    int o = i - 13920;
    bB[o] = (o < 192) ? glb_ih[o] : ghb_ih[o - 192];
  } else if (i < 17280){
    int j = i - 14208;                             // wih1T[32k][96o]
    int k = j/96, o = j - (j/96)*96;
    wih1T[j] = wih1[o*32 + k];
  } else if (i < 23424){
    int j = i - 17280;                             // wB2T[48og][32k][4]
    int og = j >> 7, rem = j & 127, k = rem >> 2, jj = rem & 3;
    int o = og*4 + jj; int g = o/96, r = o - g*96;
    wB2T[j] = glw_ih[((2+g)*96 + r)*32 + k];       // low layer1
  } else if (i < 23616){
    int o = i - 23424;
    bB2[o] = glb_ih[192 + o];                      // low layer1 bih
  }
}

// ---------- k1: gi0[b][t][96] (unchanged, verified)
__global__ __launch_bounds__(256) void k1(const float* __restrict__ mi,
    const float* __restrict__ wcT, const float* __restrict__ bc,
    float* __restrict__ gi0){
  __shared__ float mbuf[33*36];
  const int tid = threadIdx.x;
  const int b = blockIdx.x >> 3;
  const int t0 = (blockIdx.x & 7)*32;
  const int bt0 = b*256 + t0;
  for (int idx = tid; idx < 264; idx += 256){
    int row = idx >> 3, c4 = idx & 7;
    int r = t0 - 1 + row;
    float4 v = make_float4(0.f,0.f,0.f,0.f);
    if (r >= 0) v = *(const float4*)&mi[(b*256 + r)*32 + c4*4];
    *(float4*)&mbuf[row*36 + c4*4] = v;
  }
  __syncthreads();
  const int og = tid >> 3, btg = tid & 7;
  if (og >= 24) return;
  float acc[4][4];
  #pragma unroll
  for (int bj = 0; bj < 4; ++bj){ acc[bj][0]=0.f; acc[bj][1]=0.f; acc[bj][2]=0.f; acc[bj][3]=0.f; }
  for (int fq = 0; fq < 8; ++fq){
    float4 wvp[4], wvc[4];
    #pragma unroll
    for (int i = 0; i < 4; ++i){
      int f = fq*4 + i;
      wvp[i] = *(const float4*)&wcT[(2*f)*96 + og*4];
      wvc[i] = *(const float4*)&wcT[(2*f+1)*96 + og*4];
    }
    #pragma unroll
    for (int bj = 0; bj < 4; ++bj){
      int btl = btg + 8*bj;
      float4 xp = *(const float4*)&mbuf[btl*36 + fq*4];
      float4 xc = *(const float4*)&mbuf[(btl+1)*36 + fq*4];
      FMA44(acc[bj], xp, wvp);
      FMA44(acc[bj], xc, wvc);
    }
  }
  float4 bias = *(const float4*)&bc[og*4];
  #pragma unroll
  for (int bj = 0; bj < 4; ++bj){
    int btl = btg + 8*bj;
    float4 o;
    o.x = acc[bj][0] + bias.x; o.y = acc[bj][1] + bias.y;
    o.z = acc[bj][2] + bias.z; o.w = acc[bj][3] + bias.w;
    *(float4*)&gi0[(bt0 + btl)*96 + og*4] = o;
  }
}

// ---------- k2a: stage1 GRU0 only. 1 wave/batch, 48 weight floats/lane.
__global__ __launch_bounds__(64,1) void k2a(const float* __restrict__ gi0,
    const float* __restrict__ whh0, const float* __restrict__ bhh0,
    float* __restrict__ y1)
{
  const int lane = threadIdx.x;
  const int q = lane >> 5, h = lane & 31, ko = q*16;
  const int b = blockIdx.x;
  float a0h[3][16];
  #pragma unroll
  for (int g = 0; g < 3; ++g){
    const float* w0 = whh0 + (g*32+h)*32 + ko;
    #pragma unroll
    for (int k = 0; k < 16; ++k) a0h[g][k] = w0[k];
  }
  #pragma unroll
  for (int g = 0; g < 3; ++g){
    #pragma unroll
    for (int k = 0; k < 16; ++k) KEEP(a0h[g][k]);
  }
  const float bh0r = bhh0[h], bh0z = bhh0[32+h], bh0n = bhh0[64+h];

  __shared__ __attribute__((aligned(16))) float gib[2][6144];
  __shared__ __attribute__((aligned(16))) float h1arr[32];
  const float* gsrc = gi0 + b*24576;
  #pragma unroll
  for (int c0 = 0; c0 < 2; ++c0)
    for (int it = 0; it < 24; ++it)
      gload16(gsrc + c0*6144 + it*256 + lane*4, &gib[c0][it*256]);
  asm volatile("s_waitcnt vmcnt(24)" ::: "memory");

  float h1v[16];
  #pragma unroll
  for (int k = 0; k < 16; ++k) h1v[k] = 0.f;
  float h1own = 0.f;
  float c_r, c_z, c_n, p_r=0.f, p_z=0.f, p_n=0.f;

  for (int t = 0; t < Tn; ++t){
    if ((t & 63) == 0){
      if (t){
        int c = t >> 6;
        if (c < 3){
          const float* gs = gsrc + (c+1)*6144;
          for (int it = 0; it < 24; ++it)
            gload16(gs + it*256 + lane*4, &gib[(c+1)&1][it*256]);
          asm volatile("s_waitcnt vmcnt(24)" ::: "memory");
        } else {
          asm volatile("s_waitcnt vmcnt(0)" ::: "memory");
        }
      }
      const float* gt = &gib[(t>>6)&1][(t&63)*96];
      c_r = gt[h]; c_z = gt[32+h]; c_n = gt[64+h];
    } else { c_r = p_r; c_z = p_z; c_n = p_n; }
    if ((t+1) & 63){
      const float* gn = &gib[((t+1)>>6)&1][((t+1)&63)*96];
      p_r = gn[h]; p_z = gn[32+h]; p_n = gn[64+h];
    }
    float pr, pz, pn;
    DOT16(pr, h1v, a0h[0]); DOT16(pz, h1v, a0h[1]); DOT16(pn, h1v, a0h[2]);
    pr += __shfl_xor(pr,32); pz += __shfl_xor(pz,32); pn += __shfl_xor(pn,32);
    float r = fsig(c_r + pr + bh0r);
    float z = fsig(c_z + pz + bh0z);
    float nn = ftanh(c_n + r*(pn + bh0n));
    float hn1 = nn + z*(h1own - nn);
    h1own = hn1;
    h1arr[h] = hn1;
    *(float4*)&h1v[0]  = *(const float4*)&h1arr[ko+0];
    *(float4*)&h1v[4]  = *(const float4*)&h1arr[ko+4];
    *(float4*)&h1v[8]  = *(const float4*)&h1arr[ko+8];
    *(float4*)&h1v[12] = *(const float4*)&h1arr[ko+12];
    if (q == 0) y1[(b*256 + t)*32 + h] = hn1;
  }
}

// ---------- k2p: gi1SX[b][t][128] = (y1 @ wih1T + bih1 | y1). Register-tiled GEMM.
__global__ __launch_bounds__(256) void k2p(const float* __restrict__ y1,
    const float* __restrict__ wih1T, const float* __restrict__ bih1,
    float* __restrict__ gi1sx)
{
  __shared__ float xb[32*36];
  const int tid = threadIdx.x;
  const int b = blockIdx.x >> 3;
  const int t0 = (blockIdx.x & 7)*32;
  const int bt0 = b*256 + t0;
  {
    int row = tid >> 3, c4 = tid & 7;
    float4 v = *(const float4*)&y1[(bt0 + row)*32 + c4*4];
    *(float4*)&xb[row*36 + c4*4] = v;
  }
  __syncthreads();
  const int og = tid >> 3, btg = tid & 7;
  if (og < 24){
    float acc[4][4];
    #pragma unroll
    for (int bj = 0; bj < 4; ++bj){ acc[bj][0]=0.f; acc[bj][1]=0.f; acc[bj][2]=0.f; acc[bj][3]=0.f; }
    for (int kq = 0; kq < 8; ++kq){
      float4 wv[4];
      #pragma unroll
      for (int i = 0; i < 4; ++i) wv[i] = *(const float4*)&wih1T[(kq*4+i)*96 + og*4];
      #pragma unroll
      for (int bj = 0; bj < 4; ++bj){
        float4 xv = *(const float4*)&xb[(btg + 8*bj)*36 + kq*4];
        FMA44(acc[bj], xv, wv);
      }
    }
    float4 bias = *(const float4*)&bih1[og*4];
    #pragma unroll
    for (int bj = 0; bj < 4; ++bj){
      int btl = btg + 8*bj;
      float4 o;
      o.x = acc[bj][0] + bias.x; o.y = acc[bj][1] + bias.y;
      o.z = acc[bj][2] + bias.z; o.w = acc[bj][3] + bias.w;
      *(float4*)&gi1sx[(bt0 + btl)*128 + og*4] = o;
    }
  }
  // y1 passthrough into slots 96..128
  {
    int row = tid >> 3, c4 = tid & 7;
    float4 v = *(const float4*)&xb[row*36 + c4*4];
    *(float4*)&gi1sx[(bt0 + row)*128 + 96 + c4*4] = v;
  }
}

// ---------- k2b: stage1 GRU1 + add + band-mask fc. 1 wave/batch, 64 w/lane.
__global__ __launch_bounds__(64,1) void k2b(const float* __restrict__ gi1sx,
    const float* __restrict__ whh1, const float* __restrict__ bhh1,
    const float* __restrict__ fco, float* __restrict__ bmA)
{
  const int lane = threadIdx.x;
  const int q = lane >> 5, h = lane & 31, ko = q*16;
  const int b = blockIdx.x;
  float a1h[3][16], afc[16];
  #pragma unroll
  for (int g = 0; g < 3; ++g){
    const float* wh = whh1 + (g*32+h)*32 + ko;
    #pragma unroll
    for (int k = 0; k < 16; ++k) a1h[g][k] = wh[k];
  }
  #pragma unroll
  for (int k = 0; k < 16; ++k) afc[k] = fco[(ko+k)*32 + h];
  #pragma unroll
  for (int g = 0; g < 3; ++g){
    #pragma unroll
    for (int k = 0; k < 16; ++k) KEEP(a1h[g][k]);
  }
  #pragma unroll
  for (int k = 0; k < 16; ++k) KEEP(afc[k]);
  const float bh1r = bhh1[h], bh1z = bhh1[32+h], bh1n = bhh1[64+h];

  __shared__ __attribute__((aligned(16))) float gib[2][2048];
  __shared__ __attribute__((aligned(16))) float h2arr[32];
  const float* gsrc = gi1sx + b*32768;
  #pragma unroll
  for (int c0 = 0; c0 < 2; ++c0)
    for (int it = 0; it < 8; ++it)
      gload16(gsrc + c0*2048 + it*256 + lane*4, &gib[c0][it*256]);
  asm volatile("s_waitcnt vmcnt(8)" ::: "memory");

  float h2v[16];
  #pragma unroll
  for (int k = 0; k < 16; ++k) h2v[k] = 0.f;
  float h2own = 0.f;
  float c_r, c_z, c_n, p_r=0.f, p_z=0.f, p_n=0.f;

  for (int t = 0; t < Tn; ++t){
    if ((t & 15) == 0){
      if (t){
        int c = t >> 4;
        if (c < 15){
          const float* gs = gsrc + (c+1)*2048;
          for (int it = 0; it < 8; ++it)
            gload16(gs + it*256 + lane*4, &gib[(c+1)&1][it*256]);
          asm volatile("s_waitcnt vmcnt(8)" ::: "memory");
        } else {
          asm volatile("s_waitcnt vmcnt(0)" ::: "memory");
        }
      }
      const float* gt = &gib[(t>>4)&1][(t&15)*128];
      c_r = gt[h]; c_z = gt[32+h]; c_n = gt[64+h];
    } else { c_r = p_r; c_z = p_z; c_n = p_n; }
    if ((t+1) & 15){
      const float* gn = &gib[((t+1)>>4)&1][((t+1)&15)*128];
      p_r = gn[h]; p_z = gn[32+h]; p_n = gn[64+h];
    }
    const float* yb = &gib[(t>>4)&1][(t&15)*128 + 96];
    float y1v[16];
    *(float4*)&y1v[0]  = *(const float4*)&yb[ko+0];
    *(float4*)&y1v[4]  = *(const float4*)&yb[ko+4];
    *(float4*)&y1v[8]  = *(const float4*)&yb[ko+8];
    *(float4*)&y1v[12] = *(const float4*)&yb[ko+12];
    float vr, vz, vh;
    DOT16(vr, h2v, a1h[0]); DOT16(vz, h2v, a1h[1]); DOT16(vh, h2v, a1h[2]);
    vr += __shfl_xor(vr,32); vz += __shfl_xor(vz,32); vh += __shfl_xor(vh,32);
    float r1 = fsig(c_r + vr + bh1r);
    float z1 = fsig(c_z + vz + bh1z);
    float n1 = ftanh(c_n + r1*(vh + bh1n));
    float hn2 = n1 + z1*(h2own - n1);
    h2own = hn2;
    h2arr[h] = hn2;
    *(float4*)&h2v[0]  = *(const float4*)&h2arr[ko+0];
    *(float4*)&h2v[4]  = *(const float4*)&h2arr[ko+4];
    *(float4*)&h2v[8]  = *(const float4*)&h2arr[ko+8];
    *(float4*)&h2v[12] = *(const float4*)&h2arr[ko+12];
    float s = 0.f;
    #pragma unroll
    for (int k = 0; k < 16; ++k) s = fmaf(y1v[k] + h2v[k], afc[k], s);
    s += __shfl_xor(s,32);
    if (q == 0) bmA[(b*Tn + t)*32 + h] = fsig(s);
  }
}

// ---------- kP: fused low/high fc_in + PReLU + gi projections (unchanged, verified)
__global__ __launch_bounds__(256) void kP(const float* __restrict__ lpi,
    const float* __restrict__ bmA,
    const float* __restrict__ wlo, const float* __restrict__ plo,
    const float* __restrict__ whi, const float* __restrict__ phi,
    const float* __restrict__ wBT, const float* __restrict__ bB,
    float* __restrict__ giL, float* __restrict__ giH)
{
  __shared__ float xb[32*292];
  __shared__ float mb[32*100];
  const int tid = threadIdx.x;
  const int b = blockIdx.x >> 3;
  const int t0 = (blockIdx.x & 7)*32;
  const int bt0 = b*256 + t0;
  #pragma unroll
  for (int j = 0; j < 8; ++j){
    int idx = j*256 + tid;
    int row = idx >> 6, c4 = idx & 63;
    float4 v = *(const float4*)&lpi[(bt0 + row)*256 + c4*4];
    *(float4*)&xb[row*292 + c4*4] = v;
  }
  {
    int row = tid >> 3, c4 = tid & 7;
    float4 v = *(const float4*)&bmA[(bt0 + row)*32 + c4*4];
    *(float4*)&xb[row*292 + 256 + c4*4] = v;
  }
  __syncthreads();
  const int og = tid >> 3, btg = tid & 7;
  if (og < 16){
    float acc[4][4];
    #pragma unroll
    for (int bj = 0; bj < 4; ++bj){ acc[bj][0]=0.f; acc[bj][1]=0.f; acc[bj][2]=0.f; acc[bj][3]=0.f; }
    for (int kq = 0; kq < 40; ++kq){
      int k0_ = kq*4;
      int kk = (k0_ < 128) ? k0_ : k0_ + 128;
      float4 wv[4];
      #pragma unroll
      for (int i = 0; i < 4; ++i) wv[i] = *(const float4*)&wlo[(k0_+i)*64 + og*4];
      #pragma unroll
      for (int bj = 0; bj < 4; ++bj){
        float4 xv = *(const float4*)&xb[(btg + 8*bj)*292 + kk];
        FMA44(acc[bj], xv, wv);
      }
    }
    const float a = plo[0];
    #pragma unroll
    for (int bj = 0; bj < 4; ++bj){
      float4 m;
      m.x = acc[bj][0] >= 0.f ? acc[bj][0] : a*acc[bj][0];
      m.y = acc[bj][1] >= 0.f ? acc[bj][1] : a*acc[bj][1];
      m.z = acc[bj][2] >= 0.f ? acc[bj][2] : a*acc[bj][2];
      m.w = acc[bj][3] >= 0.f ? acc[bj][3] : a*acc[bj][3];
      *(float4*)&mb[(btg + 8*bj)*100 + og*4] = m;
    }
  } else if (og < 24){
    int o0 = (og - 16)*4;
    int g = o0 >> 4, r0 = o0 & 15;
    int xoff = 128 + g*80;
    float acc[4][4];
    #pragma unroll
    for (int bj = 0; bj < 4; ++bj){ acc[bj][0]=0.f; acc[bj][1]=0.f; acc[bj][2]=0.f; acc[bj][3]=0.f; }
    for (int kq = 0; kq < 20; ++kq){
      int k0_ = kq*4;
      float4 wv[4];
      #pragma unroll
      for (int i = 0; i < 4; ++i) wv[i] = *(const float4*)&whi[(g*80 + k0_ + i)*16 + r0];
      #pragma unroll
      for (int bj = 0; bj < 4; ++bj){
        float4 xv = *(const float4*)&xb[(btg + 8*bj)*292 + xoff + k0_];
        FMA44(acc[bj], xv, wv);
      }
    }
    const float a = phi[0];
    #pragma unroll
    for (int bj = 0; bj < 4; ++bj){
      float4 m;
      m.x = acc[bj][0] >= 0.f ? acc[bj][0] : a*acc[bj][0];
      m.y = acc[bj][1] >= 0.f ? acc[bj][1] : a*acc[bj][1];
      m.z = acc[bj][2] >= 0.f ? acc[bj][2] : a*acc[bj][2];
      m.w = acc[bj][3] >= 0.f ? acc[bj][3] : a*acc[bj][3];
      *(float4*)&mb[(btg + 8*bj)*100 + 64 + o0] = m;
    }
  }
  __syncthreads();
  for (int og2 = og; og2 < 72; og2 += 32){
    int woff, kbase, K, obase, dstride;
    float* dst;
    float4 bias;
    if (og2 < 48){
      woff = og2*128; kbase = (og2 >= 24) ? 32 : 0; K = 32;
      obase = og2*4; dst = giL; dstride = 192;
      bias = *(const float4*)&bB[obase];
    } else {
      int oh = og2 - 48;
      woff = 6144 + oh*64;
      int o0 = oh*4; int g = o0/48;
      kbase = 64 + g*16; K = 16;
      obase = o0; dst = giH; dstride = 96;
      bias = *(const float4*)&bB[192 + o0];
    }
    float acc[4][4];
    #pragma unroll
    for (int bj = 0; bj < 4; ++bj){ acc[bj][0]=0.f; acc[bj][1]=0.f; acc[bj][2]=0.f; acc[bj][3]=0.f; }
    for (int kq = 0; kq < K/4; ++kq){
      float4 wv[4];
      #pragma unroll
      for (int i = 0; i < 4; ++i) wv[i] = *(const float4*)&wBT[woff + (kq*4 + i)*4];
      #pragma unroll
      for (int bj = 0; bj < 4; ++bj){
        float4 xv = *(const float4*)&mb[(btg + 8*bj)*100 + kbase + kq*4];
        FMA44(acc[bj], xv, wv);
      }
    }
    #pragma unroll
    for (int bj = 0; bj < 4; ++bj){
      int btl = btg + 8*bj;
      float4 o;
      o.x = acc[bj][0] + bias.x; o.y = acc[bj][1] + bias.y;
      o.z = acc[bj][2] + bias.z; o.w = acc[bj][3] + bias.w;
      *(float4*)&dst[(bt0 + btl)*dstride + obase] = o;
    }
  }
}

// ---------- kLa: low layer0 (blocks 0..255; 2 independent waves = 2 groups) +
//             high GRU (blocks 256..383; verified pattern). 48/24 w per lane.
__global__ __launch_bounds__(128,1) void kLa(const float* __restrict__ giL,
    const float* __restrict__ giH,
    const float* __restrict__ whh, const float* __restrict__ bhh,
    const float* __restrict__ whhH, const float* __restrict__ bhhH,
    float* __restrict__ y0s, float* __restrict__ dfh)
{
  __shared__ __attribute__((aligned(16))) float smem[12352];
  const int tid = threadIdx.x;
  if (blockIdx.x < 256){
    const int g = tid >> 6;
    const int lane = tid & 63;
    const int q = lane >> 5, h = lane & 31, ko = q*16;
    const int b = blockIdx.x;
    float a0h[3][16];
    #pragma unroll
    for (int gt_ = 0; gt_ < 3; ++gt_){
      const float* w0 = whh + (g*96 + gt_*32 + h)*32 + ko;
      #pragma unroll
      for (int k = 0; k < 16; ++k) a0h[gt_][k] = w0[k];
    }
    #pragma unroll
    for (int gt_ = 0; gt_ < 3; ++gt_){
      #pragma unroll
      for (int k = 0; k < 16; ++k) KEEP(a0h[gt_][k]);
    }
    const float bh0r = bhh[g*96+h], bh0z = bhh[g*96+32+h], bh0n = bhh[g*96+64+h];
    float* gib  = smem + g*6144;
    float* h0arr = smem + 12288 + g*32;
    const float* gsrc = giL + b*49152 + g*96;
    #pragma unroll
    for (int c0 = 0; c0 < 2; ++c0)
      for (int it = 0; it < 12; ++it){
        int i = it*64 + lane;
        int toff = i/24, c4 = i - toff*24;
        gload16(gsrc + (c0*32 + toff)*192 + c4*4, &gib[c0*3072 + it*256]);
      }
    asm volatile("s_waitcnt vmcnt(12)" ::: "memory");

    float h0v[16];
    #pragma unroll
    for (int k = 0; k < 16; ++k) h0v[k] = 0.f;
    float h0own = 0.f;
    float c_r, c_z, c_n, p_r=0.f, p_z=0.f, p_n=0.f;
    const int spos = ((h&1)<<5) + (g<<4) + (h>>1);   // pre-shuffled channel

    for (int t = 0; t < Tn; ++t){
      if ((t & 31) == 0){
        if (t){
          int c = t >> 5;
          if (c < 7){
            for (int it = 0; it < 12; ++it){
              int i = it*64 + lane;
              int toff = i/24, c4 = i - toff*24;
              gload16(gsrc + ((c+1)*32 + toff)*192 + c4*4, &gib[((c+1)&1)*3072 + it*256]);
            }
            asm volatile("s_waitcnt vmcnt(12)" ::: "memory");
          } else {
            asm volatile("s_waitcnt vmcnt(0)" ::: "memory");
          }
        }
        const float* gt = &gib[((t>>5)&1)*3072 + (t&31)*96];
        c_r = gt[h]; c_z = gt[32+h]; c_n = gt[64+h];
      } else { c_r = p_r; c_z = p_z; c_n = p_n; }
      if ((t+1) & 31){
        const float* gn = &gib[(((t+1)>>5)&1)*3072 + ((t+1)&31)*96];
        p_r = gn[h]; p_z = gn[32+h]; p_n = gn[64+h];
      }
      float pr, pz, pn;
      DOT16(pr, h0v, a0h[0]); DOT16(pz, h0v, a0h[1]); DOT16(pn, h0v, a0h[2]);
      pr += __shfl_xor(pr,32); pz += __shfl_xor(pz,32); pn += __shfl_xor(pn,32);
      float r = fsig(c_r + pr + bh0r);
      float z = fsig(c_z + pz + bh0z);
      float nn = ftanh(c_n + r*(pn + bh0n));
      float hn0 = nn + z*(h0own - nn);
      h0own = hn0;
      h0arr[h] = hn0;
      *(float4*)&h0v[0]  = *(const float4*)&h0arr[ko+0];
      *(float4*)&h0v[4]  = *(const float4*)&h0arr[ko+4];
      *(float4*)&h0v[8]  = *(const float4*)&h0arr[ko+8];
      *(float4*)&h0v[12] = *(const float4*)&h0arr[ko+12];
      if (q == 0) y0s[(b*256 + t)*64 + spos] = hn0;
    }
  } else {
    const int w = tid >> 6;
    const int lane = tid & 63;
    const int g = lane >> 5, q = (lane >> 4) & 1, h = lane & 15, ko = q*8;
    const int b = (blockIdx.x - 256)*2 + w;
    float ah[3][8];
    #pragma unroll
    for (int gt_ = 0; gt_ < 3; ++gt_){
      const float* wp = whhH + (g*48 + gt_*16 + h)*16 + ko;
      #pragma unroll
      for (int k = 0; k < 8; ++k) ah[gt_][k] = wp[k];
    }
    #pragma unroll
    for (int gt_ = 0; gt_ < 3; ++gt_){
      #pragma unroll
      for (int k = 0; k < 8; ++k) KEEP(ah[gt_][k]);
    }
    const float bhr = bhhH[g*48+h], bhz = bhhH[g*48+16+h], bhn = bhhH[g*48+32+h];
    float* gib  = smem + w*6144;
    float* harr = smem + 12288 + w*32;
    const float* gsrc = giH + b*24576;
    #pragma unroll
    for (int c0 = 0; c0 < 2; ++c0)
      for (int it = 0; it < 12; ++it)
        gload16(gsrc + c0*3072 + it*256 + lane*4, &gib[c0*3072 + it*256]);
    asm volatile("s_waitcnt vmcnt(12)" ::: "memory");

    float hv[8];
    #pragma unroll
    for (int k = 0; k < 8; ++k) hv[k] = 0.f;
    float hown = 0.f;
    float c_r, c_z, c_n, p_r=0.f, p_z=0.f, p_n=0.f;

    for (int t = 0; t < Tn; ++t){
      if ((t & 31) == 0){
        if (t){
          int c = t >> 5;
          if (c < 7){
            const float* gs = gsrc + (c+1)*3072;
            for (int it = 0; it < 12; ++it)
              gload16(gs + it*256 + lane*4, &gib[((c+1)&1)*3072 + it*256]);
            asm volatile("s_waitcnt vmcnt(12)" ::: "memory");
          } else {
            asm volatile("s_waitcnt vmcnt(0)" ::: "memory");
          }
        }
        const float* gt = &gib[((t>>5)&1)*3072 + (t&31)*96 + g*48];
        c_r = gt[h]; c_z = gt[16+h]; c_n = gt[32+h];
      } else { c_r = p_r; c_z = p_z; c_n = p_n; }
      if ((t+1) & 31){
        const float* gn = &gib[(((t+1)>>5)&1)*3072 + ((t+1)&31)*96 + g*48];
        p_r = gn[h]; p_z = gn[16+h]; p_n = gn[32+h];
      }
      float pr, pz, pn;
      DOT8(pr, hv, ah[0]); DOT8(pz, hv, ah[1]); DOT8(pn, hv, ah[2]);
      pr += __shfl_xor(pr,16); pz += __shfl_xor(pz,16); pn += __shfl_xor(pn,16);
      float r = fsig(c_r + pr + bhr);
      float z = fsig(c_z + pz + bhz);
      float nn = ftanh(c_n + r*(pn + bhn));
      float hn = nn + z*(hown - nn);
      hown = hn;
      harr[g*16 + h] = hn;
      *(float4*)&hv[0] = *(const float4*)&harr[g*16 + ko + 0];
      *(float4*)&hv[4] = *(const float4*)&harr[g*16 + ko + 4];
      if (q == 0) dfh[(t*Bn + b)*32 + g*16 + h] = hn;
    }
  }
}

// ---------- kLp: gi1X[(b*2+g)][t][128] = (y0s_g @ wB2T + bB2 | y0s_g). GEMM.
__global__ __launch_bounds__(256) void kLp(const float* __restrict__ y0s,
    const float* __restrict__ wB2T, const float* __restrict__ bB2,
    float* __restrict__ gi1x)
{
  __shared__ float xb[32*68];
  const int tid = threadIdx.x;
  const int b = blockIdx.x >> 3;
  const int t0 = (blockIdx.x & 7)*32;
  const int bt0 = b*256 + t0;
  #pragma unroll
  for (int j = 0; j < 2; ++j){
    int idx = j*256 + tid;
    int row = idx >> 4, c4 = idx & 15;
    float4 v = *(const float4*)&y0s[(bt0 + row)*64 + c4*4];
    *(float4*)&xb[row*68 + c4*4] = v;
  }
  __syncthreads();
  const int og = tid >> 3, btg = tid & 7;
  #pragma unroll
  for (int pass = 0; pass < 2; ++pass){
    int og2 = og + pass*32;
    if (og2 >= 48) continue;
    int o0 = og2*4;
    int g = o0/96, r = o0 - g*96;
    float acc[4][4];
    #pragma unroll
    for (int bj = 0; bj < 4; ++bj){ acc[bj][0]=0.f; acc[bj][1]=0.f; acc[bj][2]=0.f; acc[bj][3]=0.f; }
    for (int kq = 0; kq < 8; ++kq){
      float4 wv[4];
      #pragma unroll
      for (int i = 0; i < 4; ++i) wv[i] = *(const float4*)&wB2T[og2*128 + (kq*4 + i)*4];
      #pragma unroll
      for (int bj = 0; bj < 4; ++bj){
        float4 xv = *(const float4*)&xb[(btg + 8*bj)*68 + g*32 + kq*4];
        FMA44(acc[bj], xv, wv);
      }
    }
    float4 bias = *(const float4*)&bB2[o0];
    #pragma unroll
    for (int bj = 0; bj < 4; ++bj){
      int btl = btg + 8*bj;
      float4 o;
      o.x = acc[bj][0] + bias.x; o.y = acc[bj][1] + bias.y;
      o.z = acc[bj][2] + bias.z; o.w = acc[bj][3] + bias.w;
      *(float4*)&gi1x[((b*2 + g)*256 + t0 + btl)*128 + r] = o;
    }
  }
  // y0s passthrough into slots 96..128 of each group row
  #pragma unroll
  for (int j = 0; j < 2; ++j){
    int idx = j*256 + tid;
    int row = idx >> 4, c4 = idx & 15;
    int c = c4*4, g = c >> 5;
    float4 v = *(const float4*)&xb[row*68 + c];
    *(float4*)&gi1x[((b*2 + g)*256 + t0 + row)*128 + 96 + (c & 31)] = v;
  }
}

// ---------- kLb: low layer1 + acc output. 2 independent waves = 2 groups. 48 w/lane.
__global__ __launch_bounds__(128,1) void kLb(const float* __restrict__ gi1x,
    const float* __restrict__ whh, const float* __restrict__ bhh,
    float* __restrict__ acc)
{
  __shared__ __attribute__((aligned(16))) float smem[8256];
  const int tid = threadIdx.x;
  const int g = tid >> 6;
  const int lane = tid & 63;
  const int q = lane >> 5, h = lane & 31, ko = q*16;
  const int b = blockIdx.x;
  float a1h[3][16];
  #pragma unroll
  for (int gt_ = 0; gt_ < 3; ++gt_){
    const float* wh = whh + ((2+g)*96 + gt_*32 + h)*32 + ko;
    #pragma unroll
    for (int k = 0; k < 16; ++k) a1h[gt_][k] = wh[k];
  }
  #pragma unroll
  for (int gt_ = 0; gt_ < 3; ++gt_){
    #pragma unroll
    for (int k = 0; k < 16; ++k) KEEP(a1h[gt_][k]);
  }
  const float bh1r = bhh[(2+g)*96+h], bh1z = bhh[(2+g)*96+32+h], bh1n = bhh[(2+g)*96+64+h];

  float* gib   = smem + g*4096;           // [2][2048] per wave
  float* h1arr = smem + 8192 + g*32;
  const float* gsrc = gi1x + (b*2 + g)*32768;
  #pragma unroll
  for (int c0 = 0; c0 < 2; ++c0)
    for (int it = 0; it < 8; ++it)
      gload16(gsrc + c0*2048 + it*256 + lane*4, &gib[c0*2048 + it*256]);
  asm volatile("s_waitcnt vmcnt(8)" ::: "memory");

  float h1v[16];
  #pragma unroll
  for (int k = 0; k < 16; ++k) h1v[k] = 0.f;
  float h1own = 0.f;
  float c_r, c_z, c_n, p_r=0.f, p_z=0.f, p_n=0.f;

  for (int t = 0; t < Tn; ++t){
    if ((t & 15) == 0){
      if (t){
        int c = t >> 4;
        if (c < 15){
          const float* gs = gsrc + (c+1)*2048;
          for (int it = 0; it < 8; ++it)
            gload16(gs + it*256 + lane*4, &gib[((c+1)&1)*2048 + it*256]);
          asm volatile("s_waitcnt vmcnt(8)" ::: "memory");
        } else {
          asm volatile("s_waitcnt vmcnt(0)" ::: "memory");
        }
      }
      const float* gt = &gib[((t>>4)&1)*2048 + (t&15)*128];
      c_r = gt[h]; c_z = gt[32+h]; c_n = gt[64+h];
    } else { c_r = p_r; c_z = p_z; c_n = p_n; }
    if ((t+1) & 15){
      const float* gn = &gib[(((t+1)>>4)&1)*2048 + ((t+1)&15)*128];
      p_r = gn[h]; p_z = gn[32+h]; p_n = gn[64+h];
    }
    float vr, vz, vh;
    DOT16(vr, h1v, a1h[0]); DOT16(vz, h1v, a1h[1]); DOT16(vh, h1v, a1h[2]);
    vr += __shfl_xor(vr,32); vz += __shfl_xor(vz,32); vh += __shfl_xor(vh,32);
    float r1 = fsig(c_r + vr + bh1r);
    float z1 = fsig(c_z + vz + bh1z);
    float n1 = ftanh(c_n + r1*(vh + bh1n));
    float hn1 = n1 + z1*(h1own - n1);
    h1own = hn1;
    h1arr[h] = hn1;
    *(float4*)&h1v[0]  = *(const float4*)&h1arr[ko+0];
    *(float4*)&h1v[4]  = *(const float4*)&h1arr[ko+4];
    *(float4*)&h1v[8]  = *(const float4*)&h1arr[ko+8];
    *(float4*)&h1v[12] = *(const float4*)&h1arr[ko+12];
    float yown = gib[((t>>4)&1)*2048 + (t&15)*128 + 96 + h];
    if (q == 0) acc[(t*Bn + b)*64 + g*32 + h] = yown + hn1;
  }
}

// ---------- k7: full_mask from bmA + mask fc + final fusion (unchanged, verified)
__global__ __launch_bounds__(256) void k7(const float* __restrict__ acc,
    const float* __restrict__ dfh, const float* __restrict__ bmA,
    const float* __restrict__ wlo, const float* __restrict__ whi,
    const float* __restrict__ spec, float* __restrict__ out)
{
  __shared__ float accs[32][65];
  __shared__ float dfhs[32][33];
  __shared__ float bmt[32][33];
  __shared__ float mlds[128][32];
  __shared__ float mhds[128][32];
  __shared__ float frcs[257];
  __shared__ int   ibds[257];
  const int tid = threadIdx.x;
  const int b  = blockIdx.x >> 3;
  const int t0 = (blockIdx.x & 7) * 32;
  for (int idx = tid; idx < 32*16; idx += 256){
    int tl = idx >> 4, c4 = (idx & 15)*4;
    float4 v = *(const float4*)&acc[((t0 + tl)*Bn + b)*64 + c4];
    accs[tl][c4] = v.x; accs[tl][c4+1] = v.y; accs[tl][c4+2] = v.z; accs[tl][c4+3] = v.w;
  }
  for (int idx = tid; idx < 32*8; idx += 256){
    int tl = idx >> 3, c4 = (idx & 7)*4;
    float4 v = *(const float4*)&dfh[((t0 + tl)*Bn + b)*32 + c4];
    dfhs[tl][c4] = v.x; dfhs[tl][c4+1] = v.y; dfhs[tl][c4+2] = v.z; dfhs[tl][c4+3] = v.w;
    float4 u = *(const float4*)&bmA[(b*Tn + t0 + tl)*32 + c4];
    bmt[tl][c4] = u.x; bmt[tl][c4+1] = u.y; bmt[tl][c4+2] = u.z; bmt[tl][c4+3] = u.w;
  }
  for (int f = tid; f < 257; f += 256){
    int i = 0;
    #pragma unroll
    for (int k = 1; k < 31; ++k) if (f >= EB[k]) i = k;
    ibds[f] = i;
    frcs[f] = (f < 256) ? (float)(f - EB[i]) / (float)(EB[i+1] - EB[i]) : 0.f;
  }
  __syncthreads();
  const int tl = tid & 31, fo = tid >> 5;
  {
    float p[16];
    #pragma unroll
    for (int j = 0; j < 16; ++j) p[j] = 0.f;
    for (int i = 0; i < 64; ++i){
      float a = accs[tl][i];
      const float4* wr = (const float4*)&wlo[i*128 + fo*16];
      #pragma unroll
      for (int j4 = 0; j4 < 4; ++j4){
        float4 wv = wr[j4];
        p[j4*4+0] = fmaf(a, wv.x, p[j4*4+0]);
        p[j4*4+1] = fmaf(a, wv.y, p[j4*4+1]);
        p[j4*4+2] = fmaf(a, wv.z, p[j4*4+2]);
        p[j4*4+3] = fmaf(a, wv.w, p[j4*4+3]);
      }
    }
    #pragma unroll
    for (int j = 0; j < 16; ++j) mlds[fo*16 + j][tl] = fsig(p[j]);
  }
  {
    float p[16];
    #pragma unroll
    for (int j = 0; j < 16; ++j) p[j] = 0.f;
    const int g = fo >> 2, ob = (fo & 3)*16;
    for (int i = 0; i < 16; ++i){
      float a = dfhs[tl][g*16 + i];
      const float4* wr = (const float4*)&whi[(g*16 + i)*64 + ob];
      #pragma unroll
      for (int j4 = 0; j4 < 4; ++j4){
        float4 wv = wr[j4];
        p[j4*4+0] = fmaf(a, wv.x, p[j4*4+0]);
        p[j4*4+1] = fmaf(a, wv.y, p[j4*4+1]);
        p[j4*4+2] = fmaf(a, wv.z, p[j4*4+2]);
        p[j4*4+3] = fmaf(a, wv.w, p[j4*4+3]);
      }
    }
    #pragma unroll
    for (int j = 0; j < 16; ++j) mhds[fo*16 + j][tl] = fsig(p[j]);
  }
  __syncthreads();
  float* out1 = out + 16842752;
  float* out2 = out + 2*16842752;
  float2* out3 = (float2*)(out + 3*16842752);
  const float2* sp2 = (const float2*)spec;
  for (int f = fo; f < 257; f += 8){
    int base = (b*257 + f)*Tn + t0 + tl;
    float full;
    if (f < 256){
      int i = ibds[f]; float fr = frcs[f];
      full = bmt[tl][i]*(1.f - fr) + bmt[tl][i+1]*fr;
    } else full = 0.f;
    float m = (f < 128) ? mlds[f][tl]*full
            : (f < 256 ? mhds[f-128][tl]*full : full);
    float2 s = sp2[base];
    float ox = s.x*full, oy = s.y*full;
    float sx = ox*m, sy = oy*m;
    out[base]  = full;
    out1[base] = m;
    out2[base] = sqrtf(sx*sx + sy*sy);
    out3[base] = make_float2(sx, sy);
  }
}

extern "C" void kernel_launch(void* const* d_in, const int* in_sizes, int n_in,
                              void* d_out, int out_size, void* d_ws, size_t ws_size,
                              hipStream_t stream){
  const float* mi   = (const float*)d_in[0];
  const float* spec = (const float*)d_in[1];
  const float* lpi  = (const float*)d_in[2];
  const float* s1w  = (const float*)d_in[5];
  const float* s1b  = (const float*)d_in[6];
  const float* wih0 = (const float*)d_in[7];
  const float* whh0 = (const float*)d_in[8];
  const float* bih0 = (const float*)d_in[9];
  const float* bhh0 = (const float*)d_in[10];
  const float* wih1 = (const float*)d_in[11];
  const float* whh1 = (const float*)d_in[12];
  const float* bih1 = (const float*)d_in[13];
  const float* bhh1 = (const float*)d_in[14];
  const float* fco  = (const float*)d_in[15];
  const float* filw = (const float*)d_in[16];
  const float* plo  = (const float*)d_in[17];
  const float* fihw = (const float*)d_in[18];
  const float* phi  = (const float*)d_in[19];
  const float* glw_ih = (const float*)d_in[20];
  const float* glw_hh = (const float*)d_in[21];
  const float* glb_ih = (const float*)d_in[22];
  const float* glb_hh = (const float*)d_in[23];
  const float* ghw_ih = (const float*)d_in[24];
  const float* ghw_hh = (const float*)d_in[25];
  const float* ghb_ih = (const float*)d_in[26];
  const float* ghb_hh = (const float*)d_in[27];
  const float* folw = (const float*)d_in[28];
  const float* fohw = (const float*)d_in[29];

  // big Gi scratch lives in d_out (fully overwritten by k7 at the end)
  float* outf  = (float*)d_out;
  float* giL   = outf;                    // [b][t][192] 12,582,912
  float* gi0   = outf + 12582912;         // [b][t][96]   6,291,456
  float* giH   = outf + 18874368;         // [b][t][96]   6,291,456
  float* gi1sx = outf + 25165824;         // [b][t][128]  8,388,608
  float* gi1x  = outf + 33554432;         // [b*2+g][t][128] 16,777,216

  float* ws    = (float*)d_ws;
  float* wcT   = ws;                      // 6144
  float* bc    = ws + 6144;               // 96
  float* wBT   = ws + 6240;               // 7680
  float* bB    = ws + 13920;              // 288
  float* wih1T = ws + 14208;              // 3072
  float* wB2T  = ws + 17280;              // 6144
  float* bB2   = ws + 23424;              // 192
  float* y1    = ws + 24576;              // [b][t][32]  2,097,152
  float* y0s   = ws + 2121728;            // [b][t][64]  4,194,304
  float* bmA   = ws + 6316032;            // [b][t][32]  2,097,152
  float* acc   = ws + 8413184;            // [t][b][64]  4,194,304
  float* dfh   = ws + 12607488;           // [t][b][32]  2,097,152
  float* out   = (float*)d_out;

  k0<<<93, 256, 0, stream>>>(s1w, s1b, wih0, bih0, wih1, glw_ih, glb_ih, ghw_ih, ghb_ih,
                             wcT, bc, wBT, bB, wih1T, wB2T, bB2);
  k1<<<2048, 256, 0, stream>>>(mi, wcT, bc, gi0);
  k2a<<<256, 64, 0, stream>>>(gi0, whh0, bhh0, y1);
  k2p<<<2048, 256, 0, stream>>>(y1, wih1T, bih1, gi1sx);
  k2b<<<256, 64, 0, stream>>>(gi1sx, whh1, bhh1, fco, bmA);
  kP<<<2048, 256, 0, stream>>>(lpi, bmA, filw, plo, fihw, phi, wBT, bB, giL, giH);
  kLa<<<384, 128, 0, stream>>>(giL, giH, glw_hh, glb_hh, ghw_hh, ghb_hh, y0s, dfh);
  kLp<<<2048, 256, 0, stream>>>(y0s, wB2T, bB2, gi1x);
  kLb<<<256, 128, 0, stream>>>(gi1x, glw_hh, glb_hh, acc);
  k7<<<2048, 256, 0, stream>>>(acc, dfh, bmA, folw, fohw, spec, out);
}

// Round 8
// 731.645 us; speedup vs baseline: 1.0429x; 1.0429x over previous
//
#include <hip/hip_runtime.h>
#include <math.h>

#define Bn 256
#define Tn 256

__constant__ int EB[32] = {0,3,5,8,10,13,15,18,22,25,29,33,38,42,48,53,59,66,73,80,89,97,107,117,128,140,153,167,183,199,216,256};

__device__ __forceinline__ float fsig(float x){ return __builtin_amdgcn_rcpf(1.f + __expf(-x)); }
__device__ __forceinline__ float ftanh(float x){ return 1.f - 2.f*__builtin_amdgcn_rcpf(1.f + __expf(2.f*x)); }

__device__ __forceinline__ void gload16(const float* g, float* l){
  __builtin_amdgcn_global_load_lds((const __attribute__((address_space(1))) void*)g,
                                   (__attribute__((address_space(3))) void*)l, 16, 0, 0);
}

#define KEEP(x) asm volatile("" : "+v"(x))

typedef float v2f __attribute__((ext_vector_type(2)));

#define DOT16(res, X, W) do{ float _s0=0.f,_s1=0.f,_s2=0.f,_s3=0.f; \
  _Pragma("unroll") for (int _e=0;_e<4;++_e){ \
    _s0=fmaf((X)[_e],(W)[_e],_s0); _s1=fmaf((X)[4+_e],(W)[4+_e],_s1); \
    _s2=fmaf((X)[8+_e],(W)[8+_e],_s2); _s3=fmaf((X)[12+_e],(W)[12+_e],_s3);} \
  (res)=(_s0+_s1)+(_s2+_s3); }while(0)

#define DOT8(res, X, W) do{ float _s0=0.f,_s1=0.f; \
  _Pragma("unroll") for (int _e=0;_e<4;++_e){ \
    _s0=fmaf((X)[_e],(W)[_e],_s0); _s1=fmaf((X)[4+_e],(W)[4+_e],_s1);} \
  (res)=_s0+_s1; }while(0)

#define FMA44(A, X, W) do{ \
  (A)[0]=fmaf((X).x,(W)[0].x,(A)[0]); (A)[1]=fmaf((X).x,(W)[0].y,(A)[1]); (A)[2]=fmaf((X).x,(W)[0].z,(A)[2]); (A)[3]=fmaf((X).x,(W)[0].w,(A)[3]); \
  (A)[0]=fmaf((X).y,(W)[1].x,(A)[0]); (A)[1]=fmaf((X).y,(W)[1].y,(A)[1]); (A)[2]=fmaf((X).y,(W)[1].z,(A)[2]); (A)[3]=fmaf((X).y,(W)[1].w,(A)[3]); \
  (A)[0]=fmaf((X).z,(W)[2].x,(A)[0]); (A)[1]=fmaf((X).z,(W)[2].y,(A)[1]); (A)[2]=fmaf((X).z,(W)[2].z,(A)[2]); (A)[3]=fmaf((X).z,(W)[2].w,(A)[3]); \
  (A)[0]=fmaf((X).w,(W)[3].x,(A)[0]); (A)[1]=fmaf((X).w,(W)[3].y,(A)[1]); (A)[2]=fmaf((X).w,(W)[3].z,(A)[2]); (A)[3]=fmaf((X).w,(W)[3].w,(A)[3]); \
}while(0)

// ---------- k0: weight prep (unchanged, verified)
__global__ __launch_bounds__(256) void k0(const float* __restrict__ wfc, const float* __restrict__ bfc,
    const float* __restrict__ wih0, const float* __restrict__ bih0,
    const float* __restrict__ wih1,
    const float* __restrict__ glw_ih, const float* __restrict__ glb_ih,
    const float* __restrict__ ghw_ih, const float* __restrict__ ghb_ih,
    float* __restrict__ wcT, float* __restrict__ bc,
    float* __restrict__ wBT, float* __restrict__ bB,
    float* __restrict__ wih1T, float* __restrict__ wB2T, float* __restrict__ bB2){
  int i = blockIdx.x*256 + threadIdx.x;
  if (i < 6144){
    int k = i/96, o = i - (i/96)*96;
    float s = 0.f;
    #pragma unroll
    for (int kk = 0; kk < 32; ++kk) s = fmaf(wih0[o*32+kk], wfc[kk*64+k], s);
    wcT[i] = s;
  } else if (i < 6240){
    int o = i - 6144;
    float s = bih0[o];
    #pragma unroll
    for (int kk = 0; kk < 32; ++kk) s = fmaf(wih0[o*32+kk], bfc[kk], s);
    bc[o] = s;
  } else if (i < 13920){
    int j = i - 6240;
    if (j < 6144){
      int og = j >> 7, rem = j & 127, k = rem >> 2, jj = rem & 3;
      int o = og*4 + jj; int g = o/96, r = o - g*96;
      wBT[j] = glw_ih[(g*96 + r)*32 + k];
    } else {
      int j2 = j - 6144;
      int oh = j2 >> 6, rem = j2 & 63, k = rem >> 2, jj = rem & 3;
      int o = oh*4 + jj; int g = o/48, r = o - g*48;
      wBT[j] = ghw_ih[(g*48 + r)*16 + k];
    }
  } else if (i < 14208){
    int o = i - 13920;
    bB[o] = (o < 192) ? glb_ih[o] : ghb_ih[o - 192];
  } else if (i < 17280){
    int j = i - 14208;
    int k = j/96, o = j - (j/96)*96;
    wih1T[j] = wih1[o*32 + k];
  } else if (i < 23424){
    int j = i - 17280;
    int og = j >> 7, rem = j & 127, k = rem >> 2, jj = rem & 3;
    int o = og*4 + jj; int g = o/96, r = o - g*96;
    wB2T[j] = glw_ih[((2+g)*96 + r)*32 + k];
  } else if (i < 23616){
    int o = i - 23424;
    bB2[o] = glb_ih[192 + o];
  }
}

// ---------- k1: gi0[b][t][96] (unchanged, verified)
__global__ __launch_bounds__(256) void k1(const float* __restrict__ mi,
    const float* __restrict__ wcT, const float* __restrict__ bc,
    float* __restrict__ gi0){
  __shared__ float mbuf[33*36];
  const int tid = threadIdx.x;
  const int b = blockIdx.x >> 3;
  const int t0 = (blockIdx.x & 7)*32;
  const int bt0 = b*256 + t0;
  for (int idx = tid; idx < 264; idx += 256){
    int row = idx >> 3, c4 = idx & 7;
    int r = t0 - 1 + row;
    float4 v = make_float4(0.f,0.f,0.f,0.f);
    if (r >= 0) v = *(const float4*)&mi[(b*256 + r)*32 + c4*4];
    *(float4*)&mbuf[row*36 + c4*4] = v;
  }
  __syncthreads();
  const int og = tid >> 3, btg = tid & 7;
  if (og >= 24) return;
  float acc[4][4];
  #pragma unroll
  for (int bj = 0; bj < 4; ++bj){ acc[bj][0]=0.f; acc[bj][1]=0.f; acc[bj][2]=0.f; acc[bj][3]=0.f; }
  for (int fq = 0; fq < 8; ++fq){
    float4 wvp[4], wvc[4];
    #pragma unroll
    for (int i = 0; i < 4; ++i){
      int f = fq*4 + i;
      wvp[i] = *(const float4*)&wcT[(2*f)*96 + og*4];
      wvc[i] = *(const float4*)&wcT[(2*f+1)*96 + og*4];
    }
    #pragma unroll
    for (int bj = 0; bj < 4; ++bj){
      int btl = btg + 8*bj;
      float4 xp = *(const float4*)&mbuf[btl*36 + fq*4];
      float4 xc = *(const float4*)&mbuf[(btl+1)*36 + fq*4];
      FMA44(acc[bj], xp, wvp);
      FMA44(acc[bj], xc, wvc);
    }
  }
  float4 bias = *(const float4*)&bc[og*4];
  #pragma unroll
  for (int bj = 0; bj < 4; ++bj){
    int btl = btg + 8*bj;
    float4 o;
    o.x = acc[bj][0] + bias.x; o.y = acc[bj][1] + bias.y;
    o.z = acc[bj][2] + bias.z; o.w = acc[bj][3] + bias.w;
    *(float4*)&gi0[(bt0 + btl)*96 + og*4] = o;
  }
}

// ---------- k2a: stage1 GRU0 only (unchanged, verified)
__global__ __launch_bounds__(64,1) void k2a(const float* __restrict__ gi0,
    const float* __restrict__ whh0, const float* __restrict__ bhh0,
    float* __restrict__ y1)
{
  const int lane = threadIdx.x;
  const int q = lane >> 5, h = lane & 31, ko = q*16;
  const int b = blockIdx.x;
  float a0h[3][16];
  #pragma unroll
  for (int g = 0; g < 3; ++g){
    const float* w0 = whh0 + (g*32+h)*32 + ko;
    #pragma unroll
    for (int k = 0; k < 16; ++k) a0h[g][k] = w0[k];
  }
  #pragma unroll
  for (int g = 0; g < 3; ++g){
    #pragma unroll
    for (int k = 0; k < 16; ++k) KEEP(a0h[g][k]);
  }
  const float bh0r = bhh0[h], bh0z = bhh0[32+h], bh0n = bhh0[64+h];

  __shared__ __attribute__((aligned(16))) float gib[2][6144];
  __shared__ __attribute__((aligned(16))) float h1arr[32];
  const float* gsrc = gi0 + b*24576;
  #pragma unroll
  for (int c0 = 0; c0 < 2; ++c0)
    for (int it = 0; it < 24; ++it)
      gload16(gsrc + c0*6144 + it*256 + lane*4, &gib[c0][it*256]);
  asm volatile("s_waitcnt vmcnt(24)" ::: "memory");

  float h1v[16];
  #pragma unroll
  for (int k = 0; k < 16; ++k) h1v[k] = 0.f;
  float h1own = 0.f;
  float c_r, c_z, c_n, p_r=0.f, p_z=0.f, p_n=0.f;

  for (int t = 0; t < Tn; ++t){
    if ((t & 63) == 0){
      if (t){
        int c = t >> 6;
        if (c < 3){
          const float* gs = gsrc + (c+1)*6144;
          for (int it = 0; it < 24; ++it)
            gload16(gs + it*256 + lane*4, &gib[(c+1)&1][it*256]);
          asm volatile("s_waitcnt vmcnt(24)" ::: "memory");
        } else {
          asm volatile("s_waitcnt vmcnt(0)" ::: "memory");
        }
      }
      const float* gt = &gib[(t>>6)&1][(t&63)*96];
      c_r = gt[h]; c_z = gt[32+h]; c_n = gt[64+h];
    } else { c_r = p_r; c_z = p_z; c_n = p_n; }
    if ((t+1) & 63){
      const float* gn = &gib[((t+1)>>6)&1][((t+1)&63)*96];
      p_r = gn[h]; p_z = gn[32+h]; p_n = gn[64+h];
    }
    float pr, pz, pn;
    DOT16(pr, h1v, a0h[0]); DOT16(pz, h1v, a0h[1]); DOT16(pn, h1v, a0h[2]);
    pr += __shfl_xor(pr,32); pz += __shfl_xor(pz,32); pn += __shfl_xor(pn,32);
    float r = fsig(c_r + pr + bh0r);
    float z = fsig(c_z + pz + bh0z);
    float nn = ftanh(c_n + r*(pn + bh0n));
    float hn1 = nn + z*(h1own - nn);
    h1own = hn1;
    h1arr[h] = hn1;
    *(float4*)&h1v[0]  = *(const float4*)&h1arr[ko+0];
    *(float4*)&h1v[4]  = *(const float4*)&h1arr[ko+4];
    *(float4*)&h1v[8]  = *(const float4*)&h1arr[ko+8];
    *(float4*)&h1v[12] = *(const float4*)&h1arr[ko+12];
    if (q == 0) y1[(b*256 + t)*32 + h] = hn1;
  }
}

// ---------- k2p: gi1SX (unchanged, verified)
__global__ __launch_bounds__(256) void k2p(const float* __restrict__ y1,
    const float* __restrict__ wih1T, const float* __restrict__ bih1,
    float* __restrict__ gi1sx)
{
  __shared__ float xb[32*36];
  const int tid = threadIdx.x;
  const int b = blockIdx.x >> 3;
  const int t0 = (blockIdx.x & 7)*32;
  const int bt0 = b*256 + t0;
  {
    int row = tid >> 3, c4 = tid & 7;
    float4 v = *(const float4*)&y1[(bt0 + row)*32 + c4*4];
    *(float4*)&xb[row*36 + c4*4] = v;
  }
  __syncthreads();
  const int og = tid >> 3, btg = tid & 7;
  if (og < 24){
    float acc[4][4];
    #pragma unroll
    for (int bj = 0; bj < 4; ++bj){ acc[bj][0]=0.f; acc[bj][1]=0.f; acc[bj][2]=0.f; acc[bj][3]=0.f; }
    for (int kq = 0; kq < 8; ++kq){
      float4 wv[4];
      #pragma unroll
      for (int i = 0; i < 4; ++i) wv[i] = *(const float4*)&wih1T[(kq*4+i)*96 + og*4];
      #pragma unroll
      for (int bj = 0; bj < 4; ++bj){
        float4 xv = *(const float4*)&xb[(btg + 8*bj)*36 + kq*4];
        FMA44(acc[bj], xv, wv);
      }
    }
    float4 bias = *(const float4*)&bih1[og*4];
    #pragma unroll
    for (int bj = 0; bj < 4; ++bj){
      int btl = btg + 8*bj;
      float4 o;
      o.x = acc[bj][0] + bias.x; o.y = acc[bj][1] + bias.y;
      o.z = acc[bj][2] + bias.z; o.w = acc[bj][3] + bias.w;
      *(float4*)&gi1sx[(bt0 + btl)*128 + og*4] = o;
    }
  }
  {
    int row = tid >> 3, c4 = tid & 7;
    float4 v = *(const float4*)&xb[row*36 + c4*4];
    *(float4*)&gi1sx[(bt0 + row)*128 + 96 + c4*4] = v;
  }
}

// ---------- k2b: stage1 GRU1 + add + band-mask fc (unchanged, verified)
__global__ __launch_bounds__(64,1) void k2b(const float* __restrict__ gi1sx,
    const float* __restrict__ whh1, const float* __restrict__ bhh1,
    const float* __restrict__ fco, float* __restrict__ bmA)
{
  const int lane = threadIdx.x;
  const int q = lane >> 5, h = lane & 31, ko = q*16;
  const int b = blockIdx.x;
  float a1h[3][16], afc[16];
  #pragma unroll
  for (int g = 0; g < 3; ++g){
    const float* wh = whh1 + (g*32+h)*32 + ko;
    #pragma unroll
    for (int k = 0; k < 16; ++k) a1h[g][k] = wh[k];
  }
  #pragma unroll
  for (int k = 0; k < 16; ++k) afc[k] = fco[(ko+k)*32 + h];
  #pragma unroll
  for (int g = 0; g < 3; ++g){
    #pragma unroll
    for (int k = 0; k < 16; ++k) KEEP(a1h[g][k]);
  }
  #pragma unroll
  for (int k = 0; k < 16; ++k) KEEP(afc[k]);
  const float bh1r = bhh1[h], bh1z = bhh1[32+h], bh1n = bhh1[64+h];

  __shared__ __attribute__((aligned(16))) float gib[2][2048];
  __shared__ __attribute__((aligned(16))) float h2arr[32];
  const float* gsrc = gi1sx + b*32768;
  #pragma unroll
  for (int c0 = 0; c0 < 2; ++c0)
    for (int it = 0; it < 8; ++it)
      gload16(gsrc + c0*2048 + it*256 + lane*4, &gib[c0][it*256]);
  asm volatile("s_waitcnt vmcnt(8)" ::: "memory");

  float h2v[16];
  #pragma unroll
  for (int k = 0; k < 16; ++k) h2v[k] = 0.f;
  float h2own = 0.f;
  float c_r, c_z, c_n, p_r=0.f, p_z=0.f, p_n=0.f;

  for (int t = 0; t < Tn; ++t){
    if ((t & 15) == 0){
      if (t){
        int c = t >> 4;
        if (c < 15){
          const float* gs = gsrc + (c+1)*2048;
          for (int it = 0; it < 8; ++it)
            gload16(gs + it*256 + lane*4, &gib[(c+1)&1][it*256]);
          asm volatile("s_waitcnt vmcnt(8)" ::: "memory");
        } else {
          asm volatile("s_waitcnt vmcnt(0)" ::: "memory");
        }
      }
      const float* gt = &gib[(t>>4)&1][(t&15)*128];
      c_r = gt[h]; c_z = gt[32+h]; c_n = gt[64+h];
    } else { c_r = p_r; c_z = p_z; c_n = p_n; }
    if ((t+1) & 15){
      const float* gn = &gib[((t+1)>>4)&1][((t+1)&15)*128];
      p_r = gn[h]; p_z = gn[32+h]; p_n = gn[64+h];
    }
    const float* yb = &gib[(t>>4)&1][(t&15)*128 + 96];
    float y1v[16];
    *(float4*)&y1v[0]  = *(const float4*)&yb[ko+0];
    *(float4*)&y1v[4]  = *(const float4*)&yb[ko+4];
    *(float4*)&y1v[8]  = *(const float4*)&yb[ko+8];
    *(float4*)&y1v[12] = *(const float4*)&yb[ko+12];
    float vr, vz, vh;
    DOT16(vr, h2v, a1h[0]); DOT16(vz, h2v, a1h[1]); DOT16(vh, h2v, a1h[2]);
    vr += __shfl_xor(vr,32); vz += __shfl_xor(vz,32); vh += __shfl_xor(vh,32);
    float r1 = fsig(c_r + vr + bh1r);
    float z1 = fsig(c_z + vz + bh1z);
    float n1 = ftanh(c_n + r1*(vh + bh1n));
    float hn2 = n1 + z1*(h2own - n1);
    h2own = hn2;
    h2arr[h] = hn2;
    *(float4*)&h2v[0]  = *(const float4*)&h2arr[ko+0];
    *(float4*)&h2v[4]  = *(const float4*)&h2arr[ko+4];
    *(float4*)&h2v[8]  = *(const float4*)&h2arr[ko+8];
    *(float4*)&h2v[12] = *(const float4*)&h2arr[ko+12];
    float s = 0.f;
    #pragma unroll
    for (int k = 0; k < 16; ++k) s = fmaf(y1v[k] + h2v[k], afc[k], s);
    s += __shfl_xor(s,32);
    if (q == 0) bmA[(b*Tn + t)*32 + h] = fsig(s);
  }
}

// ---------- kP: fused low/high fc_in + PReLU + gi projections (unchanged, verified)
__global__ __launch_bounds__(256) void kP(const float* __restrict__ lpi,
    const float* __restrict__ bmA,
    const float* __restrict__ wlo, const float* __restrict__ plo,
    const float* __restrict__ whi, const float* __restrict__ phi,
    const float* __restrict__ wBT, const float* __restrict__ bB,
    float* __restrict__ giL, float* __restrict__ giH)
{
  __shared__ float xb[32*292];
  __shared__ float mb[32*100];
  const int tid = threadIdx.x;
  const int b = blockIdx.x >> 3;
  const int t0 = (blockIdx.x & 7)*32;
  const int bt0 = b*256 + t0;
  #pragma unroll
  for (int j = 0; j < 8; ++j){
    int idx = j*256 + tid;
    int row = idx >> 6, c4 = idx & 63;
    float4 v = *(const float4*)&lpi[(bt0 + row)*256 + c4*4];
    *(float4*)&xb[row*292 + c4*4] = v;
  }
  {
    int row = tid >> 3, c4 = tid & 7;
    float4 v = *(const float4*)&bmA[(bt0 + row)*32 + c4*4];
    *(float4*)&xb[row*292 + 256 + c4*4] = v;
  }
  __syncthreads();
  const int og = tid >> 3, btg = tid & 7;
  if (og < 16){
    float acc[4][4];
    #pragma unroll
    for (int bj = 0; bj < 4; ++bj){ acc[bj][0]=0.f; acc[bj][1]=0.f; acc[bj][2]=0.f; acc[bj][3]=0.f; }
    for (int kq = 0; kq < 40; ++kq){
      int k0_ = kq*4;
      int kk = (k0_ < 128) ? k0_ : k0_ + 128;
      float4 wv[4];
      #pragma unroll
      for (int i = 0; i < 4; ++i) wv[i] = *(const float4*)&wlo[(k0_+i)*64 + og*4];
      #pragma unroll
      for (int bj = 0; bj < 4; ++bj){
        float4 xv = *(const float4*)&xb[(btg + 8*bj)*292 + kk];
        FMA44(acc[bj], xv, wv);
      }
    }
    const float a = plo[0];
    #pragma unroll
    for (int bj = 0; bj < 4; ++bj){
      float4 m;
      m.x = acc[bj][0] >= 0.f ? acc[bj][0] : a*acc[bj][0];
      m.y = acc[bj][1] >= 0.f ? acc[bj][1] : a*acc[bj][1];
      m.z = acc[bj][2] >= 0.f ? acc[bj][2] : a*acc[bj][2];
      m.w = acc[bj][3] >= 0.f ? acc[bj][3] : a*acc[bj][3];
      *(float4*)&mb[(btg + 8*bj)*100 + og*4] = m;
    }
  } else if (og < 24){
    int o0 = (og - 16)*4;
    int g = o0 >> 4, r0 = o0 & 15;
    int xoff = 128 + g*80;
    float acc[4][4];
    #pragma unroll
    for (int bj = 0; bj < 4; ++bj){ acc[bj][0]=0.f; acc[bj][1]=0.f; acc[bj][2]=0.f; acc[bj][3]=0.f; }
    for (int kq = 0; kq < 20; ++kq){
      int k0_ = kq*4;
      float4 wv[4];
      #pragma unroll
      for (int i = 0; i < 4; ++i) wv[i] = *(const float4*)&whi[(g*80 + k0_ + i)*16 + r0];
      #pragma unroll
      for (int bj = 0; bj < 4; ++bj){
        float4 xv = *(const float4*)&xb[(btg + 8*bj)*292 + xoff + k0_];
        FMA44(acc[bj], xv, wv);
      }
    }
    const float a = phi[0];
    #pragma unroll
    for (int bj = 0; bj < 4; ++bj){
      float4 m;
      m.x = acc[bj][0] >= 0.f ? acc[bj][0] : a*acc[bj][0];
      m.y = acc[bj][1] >= 0.f ? acc[bj][1] : a*acc[bj][1];
      m.z = acc[bj][2] >= 0.f ? acc[bj][2] : a*acc[bj][2];
      m.w = acc[bj][3] >= 0.f ? acc[bj][3] : a*acc[bj][3];
      *(float4*)&mb[(btg + 8*bj)*100 + 64 + o0] = m;
    }
  }
  __syncthreads();
  for (int og2 = og; og2 < 72; og2 += 32){
    int woff, kbase, K, obase, dstride;
    float* dst;
    float4 bias;
    if (og2 < 48){
      woff = og2*128; kbase = (og2 >= 24) ? 32 : 0; K = 32;
      obase = og2*4; dst = giL; dstride = 192;
      bias = *(const float4*)&bB[obase];
    } else {
      int oh = og2 - 48;
      woff = 6144 + oh*64;
      int o0 = oh*4; int g = o0/48;
      kbase = 64 + g*16; K = 16;
      obase = o0; dst = giH; dstride = 96;
      bias = *(const float4*)&bB[192 + o0];
    }
    float acc[4][4];
    #pragma unroll
    for (int bj = 0; bj < 4; ++bj){ acc[bj][0]=0.f; acc[bj][1]=0.f; acc[bj][2]=0.f; acc[bj][3]=0.f; }
    for (int kq = 0; kq < K/4; ++kq){
      float4 wv[4];
      #pragma unroll
      for (int i = 0; i < 4; ++i) wv[i] = *(const float4*)&wBT[woff + (kq*4 + i)*4];
      #pragma unroll
      for (int bj = 0; bj < 4; ++bj){
        float4 xv = *(const float4*)&mb[(btg + 8*bj)*100 + kbase + kq*4];
        FMA44(acc[bj], xv, wv);
      }
    }
    #pragma unroll
    for (int bj = 0; bj < 4; ++bj){
      int btl = btg + 8*bj;
      float4 o;
      o.x = acc[bj][0] + bias.x; o.y = acc[bj][1] + bias.y;
      o.z = acc[bj][2] + bias.z; o.w = acc[bj][3] + bias.w;
      *(float4*)&dst[(bt0 + btl)*dstride + obase] = o;
    }
  }
}

// ---------- kLa: low layer0 + high GRU. dfh now [b][t][32].
__global__ __launch_bounds__(128,1) void kLa(const float* __restrict__ giL,
    const float* __restrict__ giH,
    const float* __restrict__ whh, const float* __restrict__ bhh,
    const float* __restrict__ whhH, const float* __restrict__ bhhH,
    float* __restrict__ y0s, float* __restrict__ dfh)
{
  __shared__ __attribute__((aligned(16))) float smem[12352];
  const int tid = threadIdx.x;
  if (blockIdx.x < 256){
    const int g = tid >> 6;
    const int lane = tid & 63;
    const int q = lane >> 5, h = lane & 31, ko = q*16;
    const int b = blockIdx.x;
    float a0h[3][16];
    #pragma unroll
    for (int gt_ = 0; gt_ < 3; ++gt_){
      const float* w0 = whh + (g*96 + gt_*32 + h)*32 + ko;
      #pragma unroll
      for (int k = 0; k < 16; ++k) a0h[gt_][k] = w0[k];
    }
    #pragma unroll
    for (int gt_ = 0; gt_ < 3; ++gt_){
      #pragma unroll
      for (int k = 0; k < 16; ++k) KEEP(a0h[gt_][k]);
    }
    const float bh0r = bhh[g*96+h], bh0z = bhh[g*96+32+h], bh0n = bhh[g*96+64+h];
    float* gib  = smem + g*6144;
    float* h0arr = smem + 12288 + g*32;
    const float* gsrc = giL + b*49152 + g*96;
    #pragma unroll
    for (int c0 = 0; c0 < 2; ++c0)
      for (int it = 0; it < 12; ++it){
        int i = it*64 + lane;
        int toff = i/24, c4 = i - toff*24;
        gload16(gsrc + (c0*32 + toff)*192 + c4*4, &gib[c0*3072 + it*256]);
      }
    asm volatile("s_waitcnt vmcnt(12)" ::: "memory");

    float h0v[16];
    #pragma unroll
    for (int k = 0; k < 16; ++k) h0v[k] = 0.f;
    float h0own = 0.f;
    float c_r, c_z, c_n, p_r=0.f, p_z=0.f, p_n=0.f;
    const int spos = ((h&1)<<5) + (g<<4) + (h>>1);

    for (int t = 0; t < Tn; ++t){
      if ((t & 31) == 0){
        if (t){
          int c = t >> 5;
          if (c < 7){
            for (int it = 0; it < 12; ++it){
              int i = it*64 + lane;
              int toff = i/24, c4 = i - toff*24;
              gload16(gsrc + ((c+1)*32 + toff)*192 + c4*4, &gib[((c+1)&1)*3072 + it*256]);
            }
            asm volatile("s_waitcnt vmcnt(12)" ::: "memory");
          } else {
            asm volatile("s_waitcnt vmcnt(0)" ::: "memory");
          }
        }
        const float* gt = &gib[((t>>5)&1)*3072 + (t&31)*96];
        c_r = gt[h]; c_z = gt[32+h]; c_n = gt[64+h];
      } else { c_r = p_r; c_z = p_z; c_n = p_n; }
      if ((t+1) & 31){
        const float* gn = &gib[(((t+1)>>5)&1)*3072 + ((t+1)&31)*96];
        p_r = gn[h]; p_z = gn[32+h]; p_n = gn[64+h];
      }
      float pr, pz, pn;
      DOT16(pr, h0v, a0h[0]); DOT16(pz, h0v, a0h[1]); DOT16(pn, h0v, a0h[2]);
      pr += __shfl_xor(pr,32); pz += __shfl_xor(pz,32); pn += __shfl_xor(pn,32);
      float r = fsig(c_r + pr + bh0r);
      float z = fsig(c_z + pz + bh0z);
      float nn = ftanh(c_n + r*(pn + bh0n));
      float hn0 = nn + z*(h0own - nn);
      h0own = hn0;
      h0arr[h] = hn0;
      *(float4*)&h0v[0]  = *(const float4*)&h0arr[ko+0];
      *(float4*)&h0v[4]  = *(const float4*)&h0arr[ko+4];
      *(float4*)&h0v[8]  = *(const float4*)&h0arr[ko+8];
      *(float4*)&h0v[12] = *(const float4*)&h0arr[ko+12];
      if (q == 0) y0s[(b*256 + t)*64 + spos] = hn0;
    }
  } else {
    const int w = tid >> 6;
    const int lane = tid & 63;
    const int g = lane >> 5, q = (lane >> 4) & 1, h = lane & 15, ko = q*8;
    const int b = (blockIdx.x - 256)*2 + w;
    float ah[3][8];
    #pragma unroll
    for (int gt_ = 0; gt_ < 3; ++gt_){
      const float* wp = whhH + (g*48 + gt_*16 + h)*16 + ko;
      #pragma unroll
      for (int k = 0; k < 8; ++k) ah[gt_][k] = wp[k];
    }
    #pragma unroll
    for (int gt_ = 0; gt_ < 3; ++gt_){
      #pragma unroll
      for (int k = 0; k < 8; ++k) KEEP(ah[gt_][k]);
    }
    const float bhr = bhhH[g*48+h], bhz = bhhH[g*48+16+h], bhn = bhhH[g*48+32+h];
    float* gib  = smem + w*6144;
    float* harr = smem + 12288 + w*32;
    const float* gsrc = giH + b*24576;
    #pragma unroll
    for (int c0 = 0; c0 < 2; ++c0)
      for (int it = 0; it < 12; ++it)
        gload16(gsrc + c0*3072 + it*256 + lane*4, &gib[c0*3072 + it*256]);
    asm volatile("s_waitcnt vmcnt(12)" ::: "memory");

    float hv[8];
    #pragma unroll
    for (int k = 0; k < 8; ++k) hv[k] = 0.f;
    float hown = 0.f;
    float c_r, c_z, c_n, p_r=0.f, p_z=0.f, p_n=0.f;

    for (int t = 0; t < Tn; ++t){
      if ((t & 31) == 0){
        if (t){
          int c = t >> 5;
          if (c < 7){
            const float* gs = gsrc + (c+1)*3072;
            for (int it = 0; it < 12; ++it)
              gload16(gs + it*256 + lane*4, &gib[((c+1)&1)*3072 + it*256]);
            asm volatile("s_waitcnt vmcnt(12)" ::: "memory");
          } else {
            asm volatile("s_waitcnt vmcnt(0)" ::: "memory");
          }
        }
        const float* gt = &gib[((t>>5)&1)*3072 + (t&31)*96 + g*48];
        c_r = gt[h]; c_z = gt[16+h]; c_n = gt[32+h];
      } else { c_r = p_r; c_z = p_z; c_n = p_n; }
      if ((t+1) & 31){
        const float* gn = &gib[(((t+1)>>5)&1)*3072 + ((t+1)&31)*96 + g*48];
        p_r = gn[h]; p_z = gn[16+h]; p_n = gn[32+h];
      }
      float pr, pz, pn;
      DOT8(pr, hv, ah[0]); DOT8(pz, hv, ah[1]); DOT8(pn, hv, ah[2]);
      pr += __shfl_xor(pr,16); pz += __shfl_xor(pz,16); pn += __shfl_xor(pn,16);
      float r = fsig(c_r + pr + bhr);
      float z = fsig(c_z + pz + bhz);
      float nn = ftanh(c_n + r*(pn + bhn));
      float hn = nn + z*(hown - nn);
      hown = hn;
      harr[g*16 + h] = hn;
      *(float4*)&hv[0] = *(const float4*)&harr[g*16 + ko + 0];
      *(float4*)&hv[4] = *(const float4*)&harr[g*16 + ko + 4];
      if (q == 0) dfh[(b*256 + t)*32 + g*16 + h] = hn;
    }
  }
}

// ---------- kLp: gi1X (unchanged, verified)
__global__ __launch_bounds__(256) void kLp(const float* __restrict__ y0s,
    const float* __restrict__ wB2T, const float* __restrict__ bB2,
    float* __restrict__ gi1x)
{
  __shared__ float xb[32*68];
  const int tid = threadIdx.x;
  const int b = blockIdx.x >> 3;
  const int t0 = (blockIdx.x & 7)*32;
  const int bt0 = b*256 + t0;
  #pragma unroll
  for (int j = 0; j < 2; ++j){
    int idx = j*256 + tid;
    int row = idx >> 4, c4 = idx & 15;
    float4 v = *(const float4*)&y0s[(bt0 + row)*64 + c4*4];
    *(float4*)&xb[row*68 + c4*4] = v;
  }
  __syncthreads();
  const int og = tid >> 3, btg = tid & 7;
  #pragma unroll
  for (int pass = 0; pass < 2; ++pass){
    int og2 = og + pass*32;
    if (og2 >= 48) continue;
    int o0 = og2*4;
    int g = o0/96, r = o0 - g*96;
    float acc[4][4];
    #pragma unroll
    for (int bj = 0; bj < 4; ++bj){ acc[bj][0]=0.f; acc[bj][1]=0.f; acc[bj][2]=0.f; acc[bj][3]=0.f; }
    for (int kq = 0; kq < 8; ++kq){
      float4 wv[4];
      #pragma unroll
      for (int i = 0; i < 4; ++i) wv[i] = *(const float4*)&wB2T[og2*128 + (kq*4 + i)*4];
      #pragma unroll
      for (int bj = 0; bj < 4; ++bj){
        float4 xv = *(const float4*)&xb[(btg + 8*bj)*68 + g*32 + kq*4];
        FMA44(acc[bj], xv, wv);
      }
    }
    float4 bias = *(const float4*)&bB2[o0];
    #pragma unroll
    for (int bj = 0; bj < 4; ++bj){
      int btl = btg + 8*bj;
      float4 o;
      o.x = acc[bj][0] + bias.x; o.y = acc[bj][1] + bias.y;
      o.z = acc[bj][2] + bias.z; o.w = acc[bj][3] + bias.w;
      *(float4*)&gi1x[((b*2 + g)*256 + t0 + btl)*128 + r] = o;
    }
  }
  #pragma unroll
  for (int j = 0; j < 2; ++j){
    int idx = j*256 + tid;
    int row = idx >> 4, c4 = idx & 15;
    int c = c4*4, g = c >> 5;
    float4 v = *(const float4*)&xb[row*68 + c];
    *(float4*)&gi1x[((b*2 + g)*256 + t0 + row)*128 + 96 + (c & 31)] = v;
  }
}

// ---------- kLb: low layer1 + acc output. acc now [b][t][64].
__global__ __launch_bounds__(128,1) void kLb(const float* __restrict__ gi1x,
    const float* __restrict__ whh, const float* __restrict__ bhh,
    float* __restrict__ acc)
{
  __shared__ __attribute__((aligned(16))) float smem[8256];
  const int tid = threadIdx.x;
  const int g = tid >> 6;
  const int lane = tid & 63;
  const int q = lane >> 5, h = lane & 31, ko = q*16;
  const int b = blockIdx.x;
  float a1h[3][16];
  #pragma unroll
  for (int gt_ = 0; gt_ < 3; ++gt_){
    const float* wh = whh + ((2+g)*96 + gt_*32 + h)*32 + ko;
    #pragma unroll
    for (int k = 0; k < 16; ++k) a1h[gt_][k] = wh[k];
  }
  #pragma unroll
  for (int gt_ = 0; gt_ < 3; ++gt_){
    #pragma unroll
    for (int k = 0; k < 16; ++k) KEEP(a1h[gt_][k]);
  }
  const float bh1r = bhh[(2+g)*96+h], bh1z = bhh[(2+g)*96+32+h], bh1n = bhh[(2+g)*96+64+h];

  float* gib   = smem + g*4096;
  float* h1arr = smem + 8192 + g*32;
  const float* gsrc = gi1x + (b*2 + g)*32768;
  #pragma unroll
  for (int c0 = 0; c0 < 2; ++c0)
    for (int it = 0; it < 8; ++it)
      gload16(gsrc + c0*2048 + it*256 + lane*4, &gib[c0*2048 + it*256]);
  asm volatile("s_waitcnt vmcnt(8)" ::: "memory");

  float h1v[16];
  #pragma unroll
  for (int k = 0; k < 16; ++k) h1v[k] = 0.f;
  float h1own = 0.f;
  float c_r, c_z, c_n, p_r=0.f, p_z=0.f, p_n=0.f;

  for (int t = 0; t < Tn; ++t){
    if ((t & 15) == 0){
      if (t){
        int c = t >> 4;
        if (c < 15){
          const float* gs = gsrc + (c+1)*2048;
          for (int it = 0; it < 8; ++it)
            gload16(gs + it*256 + lane*4, &gib[((c+1)&1)*2048 + it*256]);
          asm volatile("s_waitcnt vmcnt(8)" ::: "memory");
        } else {
          asm volatile("s_waitcnt vmcnt(0)" ::: "memory");
        }
      }
      const float* gt = &gib[((t>>4)&1)*2048 + (t&15)*128];
      c_r = gt[h]; c_z = gt[32+h]; c_n = gt[64+h];
    } else { c_r = p_r; c_z = p_z; c_n = p_n; }
    if ((t+1) & 15){
      const float* gn = &gib[(((t+1)>>4)&1)*2048 + ((t+1)&15)*128];
      p_r = gn[h]; p_z = gn[32+h]; p_n = gn[64+h];
    }
    float vr, vz, vh;
    DOT16(vr, h1v, a1h[0]); DOT16(vz, h1v, a1h[1]); DOT16(vh, h1v, a1h[2]);
    vr += __shfl_xor(vr,32); vz += __shfl_xor(vz,32); vh += __shfl_xor(vh,32);
    float r1 = fsig(c_r + vr + bh1r);
    float z1 = fsig(c_z + vz + bh1z);
    float n1 = ftanh(c_n + r1*(vh + bh1n));
    float hn1 = n1 + z1*(h1own - n1);
    h1own = hn1;
    h1arr[h] = hn1;
    *(float4*)&h1v[0]  = *(const float4*)&h1arr[ko+0];
    *(float4*)&h1v[4]  = *(const float4*)&h1arr[ko+4];
    *(float4*)&h1v[8]  = *(const float4*)&h1arr[ko+8];
    *(float4*)&h1v[12] = *(const float4*)&h1arr[ko+12];
    float yown = gib[((t>>4)&1)*2048 + (t&15)*128 + 96 + h];
    if (q == 0) acc[(b*256 + t)*64 + g*32 + h] = yown + hn1;
  }
}

// ---------- k7: register-resident masks; no mlds/mhds LDS, no 2nd barrier;
// nontemporal output stores. Thread (tl, fo) owns f = fo*16+j (low) and 128+fo*16+j (high).
__global__ __launch_bounds__(256) void k7(const float* __restrict__ acc,
    const float* __restrict__ dfh, const float* __restrict__ bmA,
    const float* __restrict__ wlo, const float* __restrict__ whi,
    const float* __restrict__ spec, float* __restrict__ out)
{
  __shared__ float accs[32][65];
  __shared__ float dfhs[32][33];
  __shared__ float bmt[32][33];
  __shared__ float frcs[257];
  __shared__ int   ibds[257];
  const int tid = threadIdx.x;
  const int b  = blockIdx.x >> 3;
  const int t0 = (blockIdx.x & 7) * 32;
  for (int idx = tid; idx < 32*16; idx += 256){
    int tl = idx >> 4, c4 = (idx & 15)*4;
    float4 v = *(const float4*)&acc[(b*256 + t0 + tl)*64 + c4];
    accs[tl][c4] = v.x; accs[tl][c4+1] = v.y; accs[tl][c4+2] = v.z; accs[tl][c4+3] = v.w;
  }
  for (int idx = tid; idx < 32*8; idx += 256){
    int tl = idx >> 3, c4 = (idx & 7)*4;
    float4 v = *(const float4*)&dfh[(b*256 + t0 + tl)*32 + c4];
    dfhs[tl][c4] = v.x; dfhs[tl][c4+1] = v.y; dfhs[tl][c4+2] = v.z; dfhs[tl][c4+3] = v.w;
    float4 u = *(const float4*)&bmA[(b*Tn + t0 + tl)*32 + c4];
    bmt[tl][c4] = u.x; bmt[tl][c4+1] = u.y; bmt[tl][c4+2] = u.z; bmt[tl][c4+3] = u.w;
  }
  for (int f = tid; f < 257; f += 256){
    int i = 0;
    #pragma unroll
    for (int k = 1; k < 31; ++k) if (f >= EB[k]) i = k;
    ibds[f] = i;
    frcs[f] = (f < 256) ? (float)(f - EB[i]) / (float)(EB[i+1] - EB[i]) : 0.f;
  }
  __syncthreads();
  const int tl = tid & 31, fo = tid >> 5;
  float* out1 = out + 16842752;
  float* out2 = out + 2*16842752;
  float* out3 = out + 3*16842752;
  const float2* sp2 = (const float2*)spec;
  // ---- low band: f = fo*16 + j
  {
    float p[16];
    #pragma unroll
    for (int j = 0; j < 16; ++j) p[j] = 0.f;
    for (int i = 0; i < 64; ++i){
      float a = accs[tl][i];
      const float4* wr = (const float4*)&wlo[i*128 + fo*16];
      #pragma unroll
      for (int j4 = 0; j4 < 4; ++j4){
        float4 wv = wr[j4];
        p[j4*4+0] = fmaf(a, wv.x, p[j4*4+0]);
        p[j4*4+1] = fmaf(a, wv.y, p[j4*4+1]);
        p[j4*4+2] = fmaf(a, wv.z, p[j4*4+2]);
        p[j4*4+3] = fmaf(a, wv.w, p[j4*4+3]);
      }
    }
    #pragma unroll
    for (int j = 0; j < 16; ++j){
      int f = fo*16 + j;
      int i = ibds[f]; float fr = frcs[f];
      float full = bmt[tl][i]*(1.f - fr) + bmt[tl][i+1]*fr;
      float m = fsig(p[j])*full;
      int base = (b*257 + f)*Tn + t0 + tl;
      float2 s = sp2[base];
      float fm = full*m;
      float sx = s.x*fm, sy = s.y*fm;
      __builtin_nontemporal_store(full, &out[base]);
      __builtin_nontemporal_store(m, &out1[base]);
      __builtin_nontemporal_store(sqrtf(sx*sx + sy*sy), &out2[base]);
      v2f o3; o3.x = sx; o3.y = sy;
      __builtin_nontemporal_store(o3, (v2f*)&out3[base*2]);
    }
  }
  // ---- high band: f = 128 + fo*16 + j
  {
    float p[16];
    #pragma unroll
    for (int j = 0; j < 16; ++j) p[j] = 0.f;
    const int g = fo >> 2, ob = (fo & 3)*16;
    for (int i = 0; i < 16; ++i){
      float a = dfhs[tl][g*16 + i];
      const float4* wr = (const float4*)&whi[(g*16 + i)*64 + ob];
      #pragma unroll
      for (int j4 = 0; j4 < 4; ++j4){
        float4 wv = wr[j4];
        p[j4*4+0] = fmaf(a, wv.x, p[j4*4+0]);
        p[j4*4+1] = fmaf(a, wv.y, p[j4*4+1]);
        p[j4*4+2] = fmaf(a, wv.z, p[j4*4+2]);
        p[j4*4+3] = fmaf(a, wv.w, p[j4*4+3]);
      }
    }
    #pragma unroll
    for (int j = 0; j < 16; ++j){
      int f = 128 + fo*16 + j;
      int i = ibds[f]; float fr = frcs[f];
      float full = bmt[tl][i]*(1.f - fr) + bmt[tl][i+1]*fr;
      float m = fsig(p[j])*full;
      int base = (b*257 + f)*Tn + t0 + tl;
      float2 s = sp2[base];
      float fm = full*m;
      float sx = s.x*fm, sy = s.y*fm;
      __builtin_nontemporal_store(full, &out[base]);
      __builtin_nontemporal_store(m, &out1[base]);
      __builtin_nontemporal_store(sqrtf(sx*sx + sy*sy), &out2[base]);
      v2f o3; o3.x = sx; o3.y = sy;
      __builtin_nontemporal_store(o3, (v2f*)&out3[base*2]);
    }
  }
  // ---- f = 256: all outputs zero (inverse-filter column 256 is empty)
  if (fo == 0){
    int base = (b*257 + 256)*Tn + t0 + tl;
    __builtin_nontemporal_store(0.f, &out[base]);
    __builtin_nontemporal_store(0.f, &out1[base]);
    __builtin_nontemporal_store(0.f, &out2[base]);
    v2f z; z.x = 0.f; z.y = 0.f;
    __builtin_nontemporal_store(z, (v2f*)&out3[base*2]);
  }
}

extern "C" void kernel_launch(void* const* d_in, const int* in_sizes, int n_in,
                              void* d_out, int out_size, void* d_ws, size_t ws_size,
                              hipStream_t stream){
  const float* mi   = (const float*)d_in[0];
  const float* spec = (const float*)d_in[1];
  const float* lpi  = (const float*)d_in[2];
  const float* s1w  = (const float*)d_in[5];
  const float* s1b  = (const float*)d_in[6];
  const float* wih0 = (const float*)d_in[7];
  const float* whh0 = (const float*)d_in[8];
  const float* bih0 = (const float*)d_in[9];
  const float* bhh0 = (const float*)d_in[10];
  const float* wih1 = (const float*)d_in[11];
  const float* whh1 = (const float*)d_in[12];
  const float* bih1 = (const float*)d_in[13];
  const float* bhh1 = (const float*)d_in[14];
  const float* fco  = (const float*)d_in[15];
  const float* filw = (const float*)d_in[16];
  const float* plo  = (const float*)d_in[17];
  const float* fihw = (const float*)d_in[18];
  const float* phi  = (const float*)d_in[19];
  const float* glw_ih = (const float*)d_in[20];
  const float* glw_hh = (const float*)d_in[21];
  const float* glb_ih = (const float*)d_in[22];
  const float* glb_hh = (const float*)d_in[23];
  const float* ghw_ih = (const float*)d_in[24];
  const float* ghw_hh = (const float*)d_in[25];
  const float* ghb_ih = (const float*)d_in[26];
  const float* ghb_hh = (const float*)d_in[27];
  const float* folw = (const float*)d_in[28];
  const float* fohw = (const float*)d_in[29];

  // big Gi scratch lives in d_out (fully overwritten by k7 at the end)
  float* outf  = (float*)d_out;
  float* giL   = outf;                    // [b][t][192] 12,582,912
  float* gi0   = outf + 12582912;         // [b][t][96]   6,291,456
  float* giH   = outf + 18874368;         // [b][t][96]   6,291,456
  float* gi1sx = outf + 25165824;         // [b][t][128]  8,388,608
  float* gi1x  = outf + 33554432;         // [b*2+g][t][128] 16,777,216

  float* ws    = (float*)d_ws;
  float* wcT   = ws;                      // 6144
  float* bc    = ws + 6144;               // 96
  float* wBT   = ws + 6240;               // 7680
  float* bB    = ws + 13920;              // 288
  float* wih1T = ws + 14208;              // 3072
  float* wB2T  = ws + 17280;              // 6144
  float* bB2   = ws + 23424;              // 192
  float* y1    = ws + 24576;              // [b][t][32]  2,097,152
  float* y0s   = ws + 2121728;            // [b][t][64]  4,194,304
  float* bmA   = ws + 6316032;            // [b][t][32]  2,097,152
  float* acc   = ws + 8413184;            // [b][t][64]  4,194,304
  float* dfh   = ws + 12607488;           // [b][t][32]  2,097,152
  float* out   = (float*)d_out;

  k0<<<93, 256, 0, stream>>>(s1w, s1b, wih0, bih0, wih1, glw_ih, glb_ih, ghw_ih, ghb_ih,
                             wcT, bc, wBT, bB, wih1T, wB2T, bB2);
  k1<<<2048, 256, 0, stream>>>(mi, wcT, bc, gi0);
  k2a<<<256, 64, 0, stream>>>(gi0, whh0, bhh0, y1);
  k2p<<<2048, 256, 0, stream>>>(y1, wih1T, bih1, gi1sx);
  k2b<<<256, 64, 0, stream>>>(gi1sx, whh1, bhh1, fco, bmA);
  kP<<<2048, 256, 0, stream>>>(lpi, bmA, filw, plo, fihw, phi, wBT, bB, giL, giH);
  kLa<<<384, 128, 0, stream>>>(giL, giH, glw_hh, glb_hh, ghw_hh, ghb_hh, y0s, dfh);
  kLp<<<2048, 256, 0, stream>>>(y0s, wB2T, bB2, gi1x);
  kLb<<<256, 128, 0, stream>>>(gi1x, glw_hh, glb_hh, acc);
  k7<<<2048, 256, 0, stream>>>(acc, dfh, bmA, folw, fohw, spec, out);
}

// Round 9
// 578.391 us; speedup vs baseline: 1.3192x; 1.2650x over previous
//
#include <hip/hip_runtime.h>
#include <math.h>

#define Bn 256
#define Tn 256

__constant__ int EB[32] = {0,3,5,8,10,13,15,18,22,25,29,33,38,42,48,53,59,66,73,80,89,97,107,117,128,140,153,167,183,199,216,256};

__device__ __forceinline__ float fsig(float x){ return __builtin_amdgcn_rcpf(1.f + __expf(-x)); }
__device__ __forceinline__ float ftanh(float x){ return 1.f - 2.f*__builtin_amdgcn_rcpf(1.f + __expf(2.f*x)); }

__device__ __forceinline__ void gload16(const float* g, float* l){
  __builtin_amdgcn_global_load_lds((const __attribute__((address_space(1))) void*)g,
                                   (__attribute__((address_space(3))) void*)l, 16, 0, 0);
}

#define KEEP(x) asm volatile("" : "+v"(x))

typedef float v2f __attribute__((ext_vector_type(2)));

#define DOT16(res, X, W) do{ float _s0=0.f,_s1=0.f,_s2=0.f,_s3=0.f; \
  _Pragma("unroll") for (int _e=0;_e<4;++_e){ \
    _s0=fmaf((X)[_e],(W)[_e],_s0); _s1=fmaf((X)[4+_e],(W)[4+_e],_s1); \
    _s2=fmaf((X)[8+_e],(W)[8+_e],_s2); _s3=fmaf((X)[12+_e],(W)[12+_e],_s3);} \
  (res)=(_s0+_s1)+(_s2+_s3); }while(0)

#define DOT8(res, X, W) do{ float _s0=0.f,_s1=0.f; \
  _Pragma("unroll") for (int _e=0;_e<4;++_e){ \
    _s0=fmaf((X)[_e],(W)[_e],_s0); _s1=fmaf((X)[4+_e],(W)[4+_e],_s1);} \
  (res)=_s0+_s1; }while(0)

#define FMA44(A, X, W) do{ \
  (A)[0]=fmaf((X).x,(W)[0].x,(A)[0]); (A)[1]=fmaf((X).x,(W)[0].y,(A)[1]); (A)[2]=fmaf((X).x,(W)[0].z,(A)[2]); (A)[3]=fmaf((X).x,(W)[0].w,(A)[3]); \
  (A)[0]=fmaf((X).y,(W)[1].x,(A)[0]); (A)[1]=fmaf((X).y,(W)[1].y,(A)[1]); (A)[2]=fmaf((X).y,(W)[1].z,(A)[2]); (A)[3]=fmaf((X).y,(W)[1].w,(A)[3]); \
  (A)[0]=fmaf((X).z,(W)[2].x,(A)[0]); (A)[1]=fmaf((X).z,(W)[2].y,(A)[1]); (A)[2]=fmaf((X).z,(W)[2].z,(A)[2]); (A)[3]=fmaf((X).z,(W)[2].w,(A)[3]); \
  (A)[0]=fmaf((X).w,(W)[3].x,(A)[0]); (A)[1]=fmaf((X).w,(W)[3].y,(A)[1]); (A)[2]=fmaf((X).w,(W)[3].z,(A)[2]); (A)[3]=fmaf((X).w,(W)[3].w,(A)[3]); \
}while(0)

// ---------- k0: weight prep (unchanged, verified; wih1T/wB2T/bB2 now unused but harmless)
__global__ __launch_bounds__(256) void k0(const float* __restrict__ wfc, const float* __restrict__ bfc,
    const float* __restrict__ wih0, const float* __restrict__ bih0,
    const float* __restrict__ wih1,
    const float* __restrict__ glw_ih, const float* __restrict__ glb_ih,
    const float* __restrict__ ghw_ih, const float* __restrict__ ghb_ih,
    float* __restrict__ wcT, float* __restrict__ bc,
    float* __restrict__ wBT, float* __restrict__ bB,
    float* __restrict__ wih1T, float* __restrict__ wB2T, float* __restrict__ bB2){
  int i = blockIdx.x*256 + threadIdx.x;
  if (i < 6144){
    int k = i/96, o = i - (i/96)*96;
    float s = 0.f;
    #pragma unroll
    for (int kk = 0; kk < 32; ++kk) s = fmaf(wih0[o*32+kk], wfc[kk*64+k], s);
    wcT[i] = s;
  } else if (i < 6240){
    int o = i - 6144;
    float s = bih0[o];
    #pragma unroll
    for (int kk = 0; kk < 32; ++kk) s = fmaf(wih0[o*32+kk], bfc[kk], s);
    bc[o] = s;
  } else if (i < 13920){
    int j = i - 6240;
    if (j < 6144){
      int og = j >> 7, rem = j & 127, k = rem >> 2, jj = rem & 3;
      int o = og*4 + jj; int g = o/96, r = o - g*96;
      wBT[j] = glw_ih[(g*96 + r)*32 + k];
    } else {
      int j2 = j - 6144;
      int oh = j2 >> 6, rem = j2 & 63, k = rem >> 2, jj = rem & 3;
      int o = oh*4 + jj; int g = o/48, r = o - g*48;
      wBT[j] = ghw_ih[(g*48 + r)*16 + k];
    }
  } else if (i < 14208){
    int o = i - 13920;
    bB[o] = (o < 192) ? glb_ih[o] : ghb_ih[o - 192];
  } else if (i < 17280){
    int j = i - 14208;
    int k = j/96, o = j - (j/96)*96;
    wih1T[j] = wih1[o*32 + k];
  } else if (i < 23424){
    int j = i - 17280;
    int og = j >> 7, rem = j & 127, k = rem >> 2, jj = rem & 3;
    int o = og*4 + jj; int g = o/96, r = o - g*96;
    wB2T[j] = glw_ih[((2+g)*96 + r)*32 + k];
  } else if (i < 23616){
    int o = i - 23424;
    bB2[o] = glb_ih[192 + o];
  }
}

// ---------- k1: gi0[b][t][96] (unchanged, verified)
__global__ __launch_bounds__(256) void k1(const float* __restrict__ mi,
    const float* __restrict__ wcT, const float* __restrict__ bc,
    float* __restrict__ gi0){
  __shared__ float mbuf[33*36];
  const int tid = threadIdx.x;
  const int b = blockIdx.x >> 3;
  const int t0 = (blockIdx.x & 7)*32;
  const int bt0 = b*256 + t0;
  for (int idx = tid; idx < 264; idx += 256){
    int row = idx >> 3, c4 = idx & 7;
    int r = t0 - 1 + row;
    float4 v = make_float4(0.f,0.f,0.f,0.f);
    if (r >= 0) v = *(const float4*)&mi[(b*256 + r)*32 + c4*4];
    *(float4*)&mbuf[row*36 + c4*4] = v;
  }
  __syncthreads();
  const int og = tid >> 3, btg = tid & 7;
  if (og >= 24) return;
  float acc[4][4];
  #pragma unroll
  for (int bj = 0; bj < 4; ++bj){ acc[bj][0]=0.f; acc[bj][1]=0.f; acc[bj][2]=0.f; acc[bj][3]=0.f; }
  for (int fq = 0; fq < 8; ++fq){
    float4 wvp[4], wvc[4];
    #pragma unroll
    for (int i = 0; i < 4; ++i){
      int f = fq*4 + i;
      wvp[i] = *(const float4*)&wcT[(2*f)*96 + og*4];
      wvc[i] = *(const float4*)&wcT[(2*f+1)*96 + og*4];
    }
    #pragma unroll
    for (int bj = 0; bj < 4; ++bj){
      int btl = btg + 8*bj;
      float4 xp = *(const float4*)&mbuf[btl*36 + fq*4];
      float4 xc = *(const float4*)&mbuf[(btl+1)*36 + fq*4];
      FMA44(acc[bj], xp, wvp);
      FMA44(acc[bj], xc, wvc);
    }
  }
  float4 bias = *(const float4*)&bc[og*4];
  #pragma unroll
  for (int bj = 0; bj < 4; ++bj){
    int btl = btg + 8*bj;
    float4 o;
    o.x = acc[bj][0] + bias.x; o.y = acc[bj][1] + bias.y;
    o.z = acc[bj][2] + bias.z; o.w = acc[bj][3] + bias.w;
    *(float4*)&gi0[(bt0 + btl)*96 + og*4] = o;
  }
}

// ---------- kS1: stage1 double GRU + band-mask, 2 waves pipelined (wave0 = GRU0 at t,
// wave1 = GRU1+fc at t-1). Shared register set wI/wH/wF to avoid dual liveness.
__global__ __launch_bounds__(128,1) void kS1(const float* __restrict__ gi0,
    const float* __restrict__ whh0, const float* __restrict__ bhh0,
    const float* __restrict__ wih1, const float* __restrict__ whh1,
    const float* __restrict__ bih1, const float* __restrict__ bhh1,
    const float* __restrict__ fco, float* __restrict__ bmA)
{
  __shared__ __attribute__((aligned(16))) float gib[2][3072];
  __shared__ __attribute__((aligned(16))) float y1buf[2][32];
  __shared__ __attribute__((aligned(16))) float h1arr[32];
  __shared__ __attribute__((aligned(16))) float h2arr[32];
  const int tid = threadIdx.x;
  const int wid = tid >> 6;
  const int lane = tid & 63;
  const int q = lane >> 5, h = lane & 31, ko = q*16;
  const int b = blockIdx.x;
  const float* gsrc = gi0 + b*24576;

  float wI[3][16], wH[3][16], wF[16];
  float b0, b1, b2, b3;
  if (wid == 0){
    #pragma unroll
    for (int g = 0; g < 3; ++g){
      const float* w = whh0 + (g*32+h)*32 + ko;
      #pragma unroll
      for (int k = 0; k < 16; ++k){ wI[g][k] = w[k]; wH[g][k] = w[k]; }
    }
    #pragma unroll
    for (int k = 0; k < 16; ++k) wF[k] = 0.f;
    b0 = bhh0[h]; b1 = bhh0[32+h]; b2 = bhh0[64+h]; b3 = 0.f;
    #pragma unroll
    for (int c0 = 0; c0 < 2; ++c0)
      for (int it = 0; it < 12; ++it)
        gload16(gsrc + c0*3072 + it*256 + lane*4, &gib[c0][it*256]);
    asm volatile("s_waitcnt vmcnt(0)" ::: "memory");
  } else {
    #pragma unroll
    for (int g = 0; g < 3; ++g){
      const float* wi = wih1 + (g*32+h)*32 + ko;
      const float* wh = whh1 + (g*32+h)*32 + ko;
      #pragma unroll
      for (int k = 0; k < 16; ++k){ wI[g][k] = wi[k]; wH[g][k] = wh[k]; }
    }
    #pragma unroll
    for (int k = 0; k < 16; ++k) wF[k] = fco[(ko+k)*32 + h];
    b0 = bih1[h] + bhh1[h];
    b1 = bih1[32+h] + bhh1[32+h];
    b2 = bih1[64+h];
    b3 = bhh1[64+h];
  }
  #pragma unroll
  for (int g = 0; g < 3; ++g){
    #pragma unroll
    for (int k = 0; k < 16; ++k){ KEEP(wI[g][k]); KEEP(wH[g][k]); }
  }
  #pragma unroll
  for (int k = 0; k < 16; ++k) KEEP(wF[k]);
  __syncthreads();

  float hv[16];
  #pragma unroll
  for (int k = 0; k < 16; ++k) hv[k] = 0.f;
  float hOwn = 0.f;
  float c_r = 0.f, c_z = 0.f, c_n = 0.f, p_r = 0.f, p_z = 0.f, p_n = 0.f;

  for (int s = 0; s <= Tn; ++s){
    __syncthreads();
    if (wid == 0){
      if (s < Tn){
        const int t = s;
        if ((t & 31) == 0){
          if (t){
            int c = t >> 5;
            if (c < 7){
              for (int it = 0; it < 12; ++it)
                gload16(gsrc + (c+1)*3072 + it*256 + lane*4, &gib[(c+1)&1][it*256]);
            }
          }
          const float* gt = &gib[(t>>5)&1][(t&31)*96];
          c_r = gt[h]; c_z = gt[32+h]; c_n = gt[64+h];
        } else { c_r = p_r; c_z = p_z; c_n = p_n; }
        if ((t+1) & 31){
          const float* gn = &gib[((t+1)>>5)&1][((t+1)&31)*96];
          p_r = gn[h]; p_z = gn[32+h]; p_n = gn[64+h];
        }
        float pr, pz, pn;
        DOT16(pr, hv, wI[0]); DOT16(pz, hv, wI[1]); DOT16(pn, hv, wI[2]);
        pr += __shfl_xor(pr,32); pz += __shfl_xor(pz,32); pn += __shfl_xor(pn,32);
        float r = fsig(c_r + pr + b0);
        float z = fsig(c_z + pz + b1);
        float nn = ftanh(c_n + r*(pn + b2));
        float hn = nn + z*(hOwn - nn);
        hOwn = hn;
        h1arr[h] = hn;
        if (q == 0) y1buf[s & 1][h] = hn;
        *(float4*)&hv[0]  = *(const float4*)&h1arr[ko+0];
        *(float4*)&hv[4]  = *(const float4*)&h1arr[ko+4];
        *(float4*)&hv[8]  = *(const float4*)&h1arr[ko+8];
        *(float4*)&hv[12] = *(const float4*)&h1arr[ko+12];
      }
    } else {
      if (s >= 1){
        const int t = s - 1;
        const float* yb = y1buf[t & 1];
        float xv[16];
        *(float4*)&xv[0]  = *(const float4*)&yb[ko+0];
        *(float4*)&xv[4]  = *(const float4*)&yb[ko+4];
        *(float4*)&xv[8]  = *(const float4*)&yb[ko+8];
        *(float4*)&xv[12] = *(const float4*)&yb[ko+12];
        float ur, uz, ui, vr, vz, vh;
        DOT16(ur, xv, wI[0]); DOT16(uz, xv, wI[1]); DOT16(ui, xv, wI[2]);
        DOT16(vr, hv, wH[0]); DOT16(vz, hv, wH[1]); DOT16(vh, hv, wH[2]);
        float qr = ur + vr, qz = uz + vz;
        qr += __shfl_xor(qr,32); qz += __shfl_xor(qz,32);
        ui += __shfl_xor(ui,32); vh += __shfl_xor(vh,32);
        float r1 = fsig(qr + b0);
        float z1 = fsig(qz + b1);
        float n1 = ftanh(ui + b2 + r1*(vh + b3));
        float hn = n1 + z1*(hOwn - n1);
        hOwn = hn;
        h2arr[h] = hn;
        *(float4*)&hv[0]  = *(const float4*)&h2arr[ko+0];
        *(float4*)&hv[4]  = *(const float4*)&h2arr[ko+4];
        *(float4*)&hv[8]  = *(const float4*)&h2arr[ko+8];
        *(float4*)&hv[12] = *(const float4*)&h2arr[ko+12];
        float sf = 0.f;
        #pragma unroll
        for (int k = 0; k < 16; ++k) sf = fmaf(xv[k] + hv[k], wF[k], sf);
        sf += __shfl_xor(sf,32);
        if (q == 0) bmA[(b*Tn + t)*32 + h] = fsig(sf);
      }
    }
  }
}

// ---------- kP: fused low/high fc_in + PReLU + gi projections (unchanged, verified)
__global__ __launch_bounds__(256) void kP(const float* __restrict__ lpi,
    const float* __restrict__ bmA,
    const float* __restrict__ wlo, const float* __restrict__ plo,
    const float* __restrict__ whi, const float* __restrict__ phi,
    const float* __restrict__ wBT, const float* __restrict__ bB,
    float* __restrict__ giL, float* __restrict__ giH)
{
  __shared__ float xb[32*292];
  __shared__ float mb[32*100];
  const int tid = threadIdx.x;
  const int b = blockIdx.x >> 3;
  const int t0 = (blockIdx.x & 7)*32;
  const int bt0 = b*256 + t0;
  #pragma unroll
  for (int j = 0; j < 8; ++j){
    int idx = j*256 + tid;
    int row = idx >> 6, c4 = idx & 63;
    float4 v = *(const float4*)&lpi[(bt0 + row)*256 + c4*4];
    *(float4*)&xb[row*292 + c4*4] = v;
  }
  {
    int row = tid >> 3, c4 = tid & 7;
    float4 v = *(const float4*)&bmA[(bt0 + row)*32 + c4*4];
    *(float4*)&xb[row*292 + 256 + c4*4] = v;
  }
  __syncthreads();
  const int og = tid >> 3, btg = tid & 7;
  if (og < 16){
    float acc[4][4];
    #pragma unroll
    for (int bj = 0; bj < 4; ++bj){ acc[bj][0]=0.f; acc[bj][1]=0.f; acc[bj][2]=0.f; acc[bj][3]=0.f; }
    for (int kq = 0; kq < 40; ++kq){
      int k0_ = kq*4;
      int kk = (k0_ < 128) ? k0_ : k0_ + 128;
      float4 wv[4];
      #pragma unroll
      for (int i = 0; i < 4; ++i) wv[i] = *(const float4*)&wlo[(k0_+i)*64 + og*4];
      #pragma unroll
      for (int bj = 0; bj < 4; ++bj){
        float4 xv = *(const float4*)&xb[(btg + 8*bj)*292 + kk];
        FMA44(acc[bj], xv, wv);
      }
    }
    const float a = plo[0];
    #pragma unroll
    for (int bj = 0; bj < 4; ++bj){
      float4 m;
      m.x = acc[bj][0] >= 0.f ? acc[bj][0] : a*acc[bj][0];
      m.y = acc[bj][1] >= 0.f ? acc[bj][1] : a*acc[bj][1];
      m.z = acc[bj][2] >= 0.f ? acc[bj][2] : a*acc[bj][2];
      m.w = acc[bj][3] >= 0.f ? acc[bj][3] : a*acc[bj][3];
      *(float4*)&mb[(btg + 8*bj)*100 + og*4] = m;
    }
  } else if (og < 24){
    int o0 = (og - 16)*4;
    int g = o0 >> 4, r0 = o0 & 15;
    int xoff = 128 + g*80;
    float acc[4][4];
    #pragma unroll
    for (int bj = 0; bj < 4; ++bj){ acc[bj][0]=0.f; acc[bj][1]=0.f; acc[bj][2]=0.f; acc[bj][3]=0.f; }
    for (int kq = 0; kq < 20; ++kq){
      int k0_ = kq*4;
      float4 wv[4];
      #pragma unroll
      for (int i = 0; i < 4; ++i) wv[i] = *(const float4*)&whi[(g*80 + k0_ + i)*16 + r0];
      #pragma unroll
      for (int bj = 0; bj < 4; ++bj){
        float4 xv = *(const float4*)&xb[(btg + 8*bj)*292 + xoff + k0_];
        FMA44(acc[bj], xv, wv);
      }
    }
    const float a = phi[0];
    #pragma unroll
    for (int bj = 0; bj < 4; ++bj){
      float4 m;
      m.x = acc[bj][0] >= 0.f ? acc[bj][0] : a*acc[bj][0];
      m.y = acc[bj][1] >= 0.f ? acc[bj][1] : a*acc[bj][1];
      m.z = acc[bj][2] >= 0.f ? acc[bj][2] : a*acc[bj][2];
      m.w = acc[bj][3] >= 0.f ? acc[bj][3] : a*acc[bj][3];
      *(float4*)&mb[(btg + 8*bj)*100 + 64 + o0] = m;
    }
  }
  __syncthreads();
  for (int og2 = og; og2 < 72; og2 += 32){
    int woff, kbase, K, obase, dstride;
    float* dst;
    float4 bias;
    if (og2 < 48){
      woff = og2*128; kbase = (og2 >= 24) ? 32 : 0; K = 32;
      obase = og2*4; dst = giL; dstride = 192;
      bias = *(const float4*)&bB[obase];
    } else {
      int oh = og2 - 48;
      woff = 6144 + oh*64;
      int o0 = oh*4; int g = o0/48;
      kbase = 64 + g*16; K = 16;
      obase = o0; dst = giH; dstride = 96;
      bias = *(const float4*)&bB[192 + o0];
    }
    float acc[4][4];
    #pragma unroll
    for (int bj = 0; bj < 4; ++bj){ acc[bj][0]=0.f; acc[bj][1]=0.f; acc[bj][2]=0.f; acc[bj][3]=0.f; }
    for (int kq = 0; kq < K/4; ++kq){
      float4 wv[4];
      #pragma unroll
      for (int i = 0; i < 4; ++i) wv[i] = *(const float4*)&wBT[woff + (kq*4 + i)*4];
      #pragma unroll
      for (int bj = 0; bj < 4; ++bj){
        float4 xv = *(const float4*)&mb[(btg + 8*bj)*100 + kbase + kq*4];
        FMA44(acc[bj], xv, wv);
      }
    }
    #pragma unroll
    for (int bj = 0; bj < 4; ++bj){
      int btl = btg + 8*bj;
      float4 o;
      o.x = acc[bj][0] + bias.x; o.y = acc[bj][1] + bias.y;
      o.z = acc[bj][2] + bias.z; o.w = acc[bj][3] + bias.w;
      *(float4*)&dst[(bt0 + btl)*dstride + obase] = o;
    }
  }
}

// ---------- kR2: blocks 0..255 = low 2-layer GRU pipelined (4 waves: L0g0,L0g1,L1g0,L1g1);
// blocks 256..319 = high GRU (4 independent waves = 4 batches, chunk-16).
__global__ __launch_bounds__(256,1) void kR2(const float* __restrict__ giL,
    const float* __restrict__ giH,
    const float* __restrict__ wihL, const float* __restrict__ whhL,
    const float* __restrict__ bihL, const float* __restrict__ bhhL,
    const float* __restrict__ whhH, const float* __restrict__ bhhH,
    float* __restrict__ acc, float* __restrict__ dfh)
{
  __shared__ __attribute__((aligned(16))) float smem[12544];
  const int tid = threadIdx.x;
  const int wid = tid >> 6;
  const int lane = tid & 63;
  if (blockIdx.x < 256){
    const int role = wid >> 1;          // 0 = layer0, 1 = layer1
    const int g = wid & 1;
    const int q = lane >> 5, h = lane & 31, ko = q*16;
    const int b = blockIdx.x;
    float* gib   = smem + g*6144;       // [2][3072] per group, layer0 streams
    float* y0buf = smem + 12288;        // [2][64], pre-shuffled
    float* h0arr = smem + 12416 + g*32;
    float* h1l   = smem + 12480;        // [2][32]
    const float* gsrc = giL + b*49152 + g*96;

    float wI[3][16], wH[3][16];
    float b0, b1, b2, b3;
    if (role == 0){
      #pragma unroll
      for (int gt = 0; gt < 3; ++gt){
        const float* w = whhL + (g*96 + gt*32 + h)*32 + ko;
        #pragma unroll
        for (int k = 0; k < 16; ++k){ wI[gt][k] = w[k]; wH[gt][k] = w[k]; }
      }
      b0 = bhhL[g*96+h]; b1 = bhhL[g*96+32+h]; b2 = bhhL[g*96+64+h]; b3 = 0.f;
      #pragma unroll
      for (int c0 = 0; c0 < 2; ++c0)
        for (int it = 0; it < 12; ++it){
          int i = it*64 + lane;
          int toff = i/24, c4 = i - toff*24;
          gload16(gsrc + (c0*32 + toff)*192 + c4*4, &gib[c0*3072 + it*256]);
        }
      asm volatile("s_waitcnt vmcnt(0)" ::: "memory");
    } else {
      #pragma unroll
      for (int gt = 0; gt < 3; ++gt){
        const float* wi = wihL + ((2+g)*96 + gt*32 + h)*32 + ko;
        const float* wh = whhL + ((2+g)*96 + gt*32 + h)*32 + ko;
        #pragma unroll
        for (int k = 0; k < 16; ++k){ wI[gt][k] = wi[k]; wH[gt][k] = wh[k]; }
      }
      b0 = bihL[(2+g)*96+h]    + bhhL[(2+g)*96+h];
      b1 = bihL[(2+g)*96+32+h] + bhhL[(2+g)*96+32+h];
      b2 = bihL[(2+g)*96+64+h];
      b3 = bhhL[(2+g)*96+64+h];
    }
    #pragma unroll
    for (int gt = 0; gt < 3; ++gt){
      #pragma unroll
      for (int k = 0; k < 16; ++k){ KEEP(wI[gt][k]); KEEP(wH[gt][k]); }
    }
    __syncthreads();

    float hv[16];
    #pragma unroll
    for (int k = 0; k < 16; ++k) hv[k] = 0.f;
    float hOwn = 0.f;
    float c_r = 0.f, c_z = 0.f, c_n = 0.f, p_r = 0.f, p_z = 0.f, p_n = 0.f;
    const int spos = ((h&1)<<5) + (g<<4) + (h>>1);

    for (int s = 0; s <= Tn; ++s){
      __syncthreads();
      if (role == 0){
        if (s < Tn){
          const int t = s;
          if ((t & 31) == 0){
            if (t){
              int c = t >> 5;
              if (c < 7){
                for (int it = 0; it < 12; ++it){
                  int i = it*64 + lane;
                  int toff = i/24, c4 = i - toff*24;
                  gload16(gsrc + ((c+1)*32 + toff)*192 + c4*4, &gib[((c+1)&1)*3072 + it*256]);
                }
              }
            }
            const float* gt = &gib[((t>>5)&1)*3072 + (t&31)*96];
            c_r = gt[h]; c_z = gt[32+h]; c_n = gt[64+h];
          } else { c_r = p_r; c_z = p_z; c_n = p_n; }
          if ((t+1) & 31){
            const float* gn = &gib[(((t+1)>>5)&1)*3072 + ((t+1)&31)*96];
            p_r = gn[h]; p_z = gn[32+h]; p_n = gn[64+h];
          }
          float pr, pz, pn;
          DOT16(pr, hv, wI[0]); DOT16(pz, hv, wI[1]); DOT16(pn, hv, wI[2]);
          pr += __shfl_xor(pr,32); pz += __shfl_xor(pz,32); pn += __shfl_xor(pn,32);
          float r = fsig(c_r + pr + b0);
          float z = fsig(c_z + pz + b1);
          float nn = ftanh(c_n + r*(pn + b2));
          float hn = nn + z*(hOwn - nn);
          hOwn = hn;
          h0arr[h] = hn;
          if (q == 0) y0buf[(s&1)*64 + spos] = hn;
          *(float4*)&hv[0]  = *(const float4*)&h0arr[ko+0];
          *(float4*)&hv[4]  = *(const float4*)&h0arr[ko+4];
          *(float4*)&hv[8]  = *(const float4*)&h0arr[ko+8];
          *(float4*)&hv[12] = *(const float4*)&h0arr[ko+12];
        }
      } else {
        if (s >= 1){
          const int t = s - 1;
          const float* yb = &y0buf[(t&1)*64];
          float xv[16];
          *(float4*)&xv[0]  = *(const float4*)&yb[g*32 + ko + 0];
          *(float4*)&xv[4]  = *(const float4*)&yb[g*32 + ko + 4];
          *(float4*)&xv[8]  = *(const float4*)&yb[g*32 + ko + 8];
          *(float4*)&xv[12] = *(const float4*)&yb[g*32 + ko + 12];
          float yown = yb[g*32 + h];
          float ur, uz, ui, vr, vz, vh;
          DOT16(ur, xv, wI[0]); DOT16(uz, xv, wI[1]); DOT16(ui, xv, wI[2]);
          DOT16(vr, hv, wH[0]); DOT16(vz, hv, wH[1]); DOT16(vh, hv, wH[2]);
          float qr = ur + vr, qz = uz + vz;
          qr += __shfl_xor(qr,32); qz += __shfl_xor(qz,32);
          ui += __shfl_xor(ui,32); vh += __shfl_xor(vh,32);
          float r1 = fsig(qr + b0);
          float z1 = fsig(qz + b1);
          float n1 = ftanh(ui + b2 + r1*(vh + b3));
          float hn = n1 + z1*(hOwn - n1);
          hOwn = hn;
          h1l[g*32 + h] = hn;
          *(float4*)&hv[0]  = *(const float4*)&h1l[g*32 + ko+0];
          *(float4*)&hv[4]  = *(const float4*)&h1l[g*32 + ko+4];
          *(float4*)&hv[8]  = *(const float4*)&h1l[g*32 + ko+8];
          *(float4*)&hv[12] = *(const float4*)&h1l[g*32 + ko+12];
          if (q == 0) acc[(b*256 + t)*64 + g*32 + h] = yown + hn;
        }
      }
    }
  } else {
    // ---------- high path: 4 independent waves, chunk-16, no barriers
    const int g = lane >> 5, qh = (lane >> 4) & 1, h = lane & 15, ko = qh*8;
    const int b = (blockIdx.x - 256)*4 + wid;
    float* gib  = smem + wid*3072;      // [2][1536]
    float* harr = smem + 12288 + wid*32;
    float ah[3][8];
    #pragma unroll
    for (int gt = 0; gt < 3; ++gt){
      const float* wp = whhH + (g*48 + gt*16 + h)*16 + ko;
      #pragma unroll
      for (int k = 0; k < 8; ++k) ah[gt][k] = wp[k];
    }
    #pragma unroll
    for (int gt = 0; gt < 3; ++gt){
      #pragma unroll
      for (int k = 0; k < 8; ++k) KEEP(ah[gt][k]);
    }
    const float bhr = bhhH[g*48+h], bhz = bhhH[g*48+16+h], bhn = bhhH[g*48+32+h];
    const float* gsrc = giH + b*24576;
    #pragma unroll
    for (int c0 = 0; c0 < 2; ++c0)
      for (int it = 0; it < 6; ++it)
        gload16(gsrc + c0*1536 + it*256 + lane*4, &gib[c0*1536 + it*256]);
    asm volatile("s_waitcnt vmcnt(0)" ::: "memory");

    float hv[8];
    #pragma unroll
    for (int k = 0; k < 8; ++k) hv[k] = 0.f;
    float hOwn = 0.f;
    float c_r = 0.f, c_z = 0.f, c_n = 0.f, p_r = 0.f, p_z = 0.f, p_n = 0.f;

    for (int t = 0; t < Tn; ++t){
      if ((t & 15) == 0){
        if (t){
          int c = t >> 4;
          if (c < 15){
            const float* gs = gsrc + (c+1)*1536;
            for (int it = 0; it < 6; ++it)
              gload16(gs + it*256 + lane*4, &gib[((c+1)&1)*1536 + it*256]);
            asm volatile("s_waitcnt vmcnt(6)" ::: "memory");
          } else {
            asm volatile("s_waitcnt vmcnt(0)" ::: "memory");
          }
        }
        const float* gt = &gib[((t>>4)&1)*1536 + (t&15)*96 + g*48];
        c_r = gt[h]; c_z = gt[16+h]; c_n = gt[32+h];
      } else { c_r = p_r; c_z = p_z; c_n = p_n; }
      if ((t+1) & 15){
        const float* gn = &gib[(((t+1)>>4)&1)*1536 + ((t+1)&15)*96 + g*48];
        p_r = gn[h]; p_z = gn[16+h]; p_n = gn[32+h];
      }
      float pr, pz, pn;
      DOT8(pr, hv, ah[0]); DOT8(pz, hv, ah[1]); DOT8(pn, hv, ah[2]);
      pr += __shfl_xor(pr,16); pz += __shfl_xor(pz,16); pn += __shfl_xor(pn,16);
      float r = fsig(c_r + pr + bhr);
      float z = fsig(c_z + pz + bhz);
      float nn = ftanh(c_n + r*(pn + bhn));
      float hn = nn + z*(hOwn - nn);
      hOwn = hn;
      harr[g*16 + h] = hn;
      *(float4*)&hv[0] = *(const float4*)&harr[g*16 + ko + 0];
      *(float4*)&hv[4] = *(const float4*)&harr[g*16 + ko + 4];
      if (qh == 0) dfh[(b*256 + t)*32 + g*16 + h] = hn;
    }
  }
}

// ---------- k7: register-resident masks + nontemporal stores (unchanged, verified)
__global__ __launch_bounds__(256) void k7(const float* __restrict__ acc,
    const float* __restrict__ dfh, const float* __restrict__ bmA,
    const float* __restrict__ wlo, const float* __restrict__ whi,
    const float* __restrict__ spec, float* __restrict__ out)
{
  __shared__ float accs[32][65];
  __shared__ float dfhs[32][33];
  __shared__ float bmt[32][33];
  __shared__ float frcs[257];
  __shared__ int   ibds[257];
  const int tid = threadIdx.x;
  const int b  = blockIdx.x >> 3;
  const int t0 = (blockIdx.x & 7) * 32;
  for (int idx = tid; idx < 32*16; idx += 256){
    int tl = idx >> 4, c4 = (idx & 15)*4;
    float4 v = *(const float4*)&acc[(b*256 + t0 + tl)*64 + c4];
    accs[tl][c4] = v.x; accs[tl][c4+1] = v.y; accs[tl][c4+2] = v.z; accs[tl][c4+3] = v.w;
  }
  for (int idx = tid; idx < 32*8; idx += 256){
    int tl = idx >> 3, c4 = (idx & 7)*4;
    float4 v = *(const float4*)&dfh[(b*256 + t0 + tl)*32 + c4];
    dfhs[tl][c4] = v.x; dfhs[tl][c4+1] = v.y; dfhs[tl][c4+2] = v.z; dfhs[tl][c4+3] = v.w;
    float4 u = *(const float4*)&bmA[(b*Tn + t0 + tl)*32 + c4];
    bmt[tl][c4] = u.x; bmt[tl][c4+1] = u.y; bmt[tl][c4+2] = u.z; bmt[tl][c4+3] = u.w;
  }
  for (int f = tid; f < 257; f += 256){
    int i = 0;
    #pragma unroll
    for (int k = 1; k < 31; ++k) if (f >= EB[k]) i = k;
    ibds[f] = i;
    frcs[f] = (f < 256) ? (float)(f - EB[i]) / (float)(EB[i+1] - EB[i]) : 0.f;
  }
  __syncthreads();
  const int tl = tid & 31, fo = tid >> 5;
  float* out1 = out + 16842752;
  float* out2 = out + 2*16842752;
  float* out3 = out + 3*16842752;
  const float2* sp2 = (const float2*)spec;
  {
    float p[16];
    #pragma unroll
    for (int j = 0; j < 16; ++j) p[j] = 0.f;
    for (int i = 0; i < 64; ++i){
      float a = accs[tl][i];
      const float4* wr = (const float4*)&wlo[i*128 + fo*16];
      #pragma unroll
      for (int j4 = 0; j4 < 4; ++j4){
        float4 wv = wr[j4];
        p[j4*4+0] = fmaf(a, wv.x, p[j4*4+0]);
        p[j4*4+1] = fmaf(a, wv.y, p[j4*4+1]);
        p[j4*4+2] = fmaf(a, wv.z, p[j4*4+2]);
        p[j4*4+3] = fmaf(a, wv.w, p[j4*4+3]);
      }
    }
    #pragma unroll
    for (int j = 0; j < 16; ++j){
      int f = fo*16 + j;
      int i = ibds[f]; float fr = frcs[f];
      float full = bmt[tl][i]*(1.f - fr) + bmt[tl][i+1]*fr;
      float m = fsig(p[j])*full;
      int base = (b*257 + f)*Tn + t0 + tl;
      float2 s = sp2[base];
      float fm = full*m;
      float sx = s.x*fm, sy = s.y*fm;
      __builtin_nontemporal_store(full, &out[base]);
      __builtin_nontemporal_store(m, &out1[base]);
      __builtin_nontemporal_store(sqrtf(sx*sx + sy*sy), &out2[base]);
      v2f o3; o3.x = sx; o3.y = sy;
      __builtin_nontemporal_store(o3, (v2f*)&out3[base*2]);
    }
  }
  {
    float p[16];
    #pragma unroll
    for (int j = 0; j < 16; ++j) p[j] = 0.f;
    const int g = fo >> 2, ob = (fo & 3)*16;
    for (int i = 0; i < 16; ++i){
      float a = dfhs[tl][g*16 + i];
      const float4* wr = (const float4*)&whi[(g*16 + i)*64 + ob];
      #pragma unroll
      for (int j4 = 0; j4 < 4; ++j4){
        float4 wv = wr[j4];
        p[j4*4+0] = fmaf(a, wv.x, p[j4*4+0]);
        p[j4*4+1] = fmaf(a, wv.y, p[j4*4+1]);
        p[j4*4+2] = fmaf(a, wv.z, p[j4*4+2]);
        p[j4*4+3] = fmaf(a, wv.w, p[j4*4+3]);
      }
    }
    #pragma unroll
    for (int j = 0; j < 16; ++j){
      int f = 128 + fo*16 + j;
      int i = ibds[f]; float fr = frcs[f];
      float full = bmt[tl][i]*(1.f - fr) + bmt[tl][i+1]*fr;
      float m = fsig(p[j])*full;
      int base = (b*257 + f)*Tn + t0 + tl;
      float2 s = sp2[base];
      float fm = full*m;
      float sx = s.x*fm, sy = s.y*fm;
      __builtin_nontemporal_store(full, &out[base]);
      __builtin_nontemporal_store(m, &out1[base]);
      __builtin_nontemporal_store(sqrtf(sx*sx + sy*sy), &out2[base]);
      v2f o3; o3.x = sx; o3.y = sy;
      __builtin_nontemporal_store(o3, (v2f*)&out3[base*2]);
    }
  }
  if (fo == 0){
    int base = (b*257 + 256)*Tn + t0 + tl;
    __builtin_nontemporal_store(0.f, &out[base]);
    __builtin_nontemporal_store(0.f, &out1[base]);
    __builtin_nontemporal_store(0.f, &out2[base]);
    v2f z; z.x = 0.f; z.y = 0.f;
    __builtin_nontemporal_store(z, (v2f*)&out3[base*2]);
  }
}

extern "C" void kernel_launch(void* const* d_in, const int* in_sizes, int n_in,
                              void* d_out, int out_size, void* d_ws, size_t ws_size,
                              hipStream_t stream){
  const float* mi   = (const float*)d_in[0];
  const float* spec = (const float*)d_in[1];
  const float* lpi  = (const float*)d_in[2];
  const float* s1w  = (const float*)d_in[5];
  const float* s1b  = (const float*)d_in[6];
  const float* wih0 = (const float*)d_in[7];
  const float* whh0 = (const float*)d_in[8];
  const float* bih0 = (const float*)d_in[9];
  const float* bhh0 = (const float*)d_in[10];
  const float* wih1 = (const float*)d_in[11];
  const float* whh1 = (const float*)d_in[12];
  const float* bih1 = (const float*)d_in[13];
  const float* bhh1 = (const float*)d_in[14];
  const float* fco  = (const float*)d_in[15];
  const float* filw = (const float*)d_in[16];
  const float* plo  = (const float*)d_in[17];
  const float* fihw = (const float*)d_in[18];
  const float* phi  = (const float*)d_in[19];
  const float* glw_ih = (const float*)d_in[20];
  const float* glw_hh = (const float*)d_in[21];
  const float* glb_ih = (const float*)d_in[22];
  const float* glb_hh = (const float*)d_in[23];
  const float* ghw_ih = (const float*)d_in[24];
  const float* ghw_hh = (const float*)d_in[25];
  const float* ghb_ih = (const float*)d_in[26];
  const float* ghb_hh = (const float*)d_in[27];
  const float* folw = (const float*)d_in[28];
  const float* fohw = (const float*)d_in[29];

  // big Gi scratch lives in d_out (fully overwritten by k7 at the end)
  float* outf = (float*)d_out;
  float* giL  = outf;                     // [b][t][192] 12,582,912
  float* gi0  = outf + 12582912;          // [b][t][96]   6,291,456
  float* giH  = outf + 18874368;          // [b][t][96]   6,291,456

  float* ws    = (float*)d_ws;
  float* wcT   = ws;                      // 6144
  float* bc    = ws + 6144;               // 96
  float* wBT   = ws + 6240;               // 7680
  float* bB    = ws + 13920;              // 288
  float* wih1T = ws + 14208;              // 3072 (unused)
  float* wB2T  = ws + 17280;              // 6144 (unused)
  float* bB2   = ws + 23424;              // 192  (unused)
  float* bmA   = ws + 24576;              // [b][t][32]  2,097,152
  float* acc   = ws + 2121728;            // [b][t][64]  4,194,304
  float* dfh   = ws + 6316032;            // [b][t][32]  2,097,152
  float* out   = (float*)d_out;

  k0<<<93, 256, 0, stream>>>(s1w, s1b, wih0, bih0, wih1, glw_ih, glb_ih, ghw_ih, ghb_ih,
                             wcT, bc, wBT, bB, wih1T, wB2T, bB2);
  k1<<<2048, 256, 0, stream>>>(mi, wcT, bc, gi0);
  kS1<<<256, 128, 0, stream>>>(gi0, whh0, bhh0, wih1, whh1, bih1, bhh1, fco, bmA);
  kP<<<2048, 256, 0, stream>>>(lpi, bmA, filw, plo, fihw, phi, wBT, bB, giL, giH);
  kR2<<<320, 256, 0, stream>>>(giL, giH, glw_ih, glw_hh, glb_ih, glb_hh,
                               ghw_hh, ghb_hh, acc, dfh);
  k7<<<2048, 256, 0, stream>>>(acc, dfh, bmA, folw, fohw, spec, out);
}